// Round 17
// baseline (1674.564 us; speedup 1.0000x reference)
//
#include <hip/hip_runtime.h>
#include <hip/hip_fp8.h>
#include <cmath>

#define SS 512
#define BB 32
#define EE 128
#define HH 256
#define VV 10000
#define NROWS (SS*BB)   // 16384
#define VPAD 10048
#define NT8 (VPAD/16)   // 628 fp8 B-tiles

typedef unsigned short ushort_t;
typedef unsigned char uchar_t;
typedef __attribute__((ext_vector_type(8))) short bf16x8;
typedef __attribute__((ext_vector_type(8))) int i32x8;
typedef __attribute__((ext_vector_type(4))) float f32x4;

#define MFMA(a,b,c)  __builtin_amdgcn_mfma_f32_16x16x32_bf16((a),(b),(c),0,0,0)
// fp8 x fp8, K=128, unit scales (E8M0 127 = 1.0) -> numerically plain fp8 matmul
#define MFMAS(a,b,c) __builtin_amdgcn_mfma_scale_f32_16x16x128_f8f6f4((a),(b),(c),0,0,0,0x7F7F7F7F,0,0x7F7F7F7F)

__device__ __forceinline__ ushort_t f2bf(float x) {
    unsigned u = __float_as_uint(x);
    u = (u + 0x7FFFu + ((u >> 16) & 1u)) >> 16;   // RNE
    return (ushort_t)u;
}
__device__ __forceinline__ float bf2f(ushort_t h) {
    return __uint_as_float(((unsigned)h) << 16);
}
__device__ __forceinline__ uchar_t f2fp8(float x) {
    __hip_fp8_e4m3 t(x);                           // OCP e4m3
    return (uchar_t)t.__x;
}
__device__ __forceinline__ float sigf(float x) { return 1.0f / (1.0f + __expf(-x)); }
__device__ __forceinline__ float tanhf_(float x) { return 1.0f - 2.0f / (__expf(2.0f * x) + 1.0f); }

// assemble a 32-B fp8 fragment from two 16-B halves 1024 B apart (LDS or global)
__device__ __forceinline__ i32x8 ldfrag(const uchar_t* base, int lane) {
    i32x8 r;
    ((uint4*)&r)[0] = *(const uint4*)(base + lane * 16);
    ((uint4*)&r)[1] = *(const uint4*)(base + 1024 + lane * 16);
    return r;
}

// ---------------- k0 x-part transpose: fp32 [128 k][1024 n] -> bf16 [1024 n][128 k] ----
__global__ __launch_bounds__(256)
void wtx(const float* __restrict__ src, ushort_t* __restrict__ dst)
{
    __shared__ float tile[64][65];
    const int tid = threadIdx.x;
    const int n0 = blockIdx.x * 64, k0_ = blockIdx.y * 64;
    for (int i = tid; i < 4096; i += 256) {
        const int kk = i >> 6, nn = i & 63;
        tile[kk][nn] = src[(size_t)(k0_ + kk) * 1024 + n0 + nn];
    }
    __syncthreads();
    for (int i = tid; i < 4096; i += 256) {
        const int nn = i >> 6, kk = i & 63;
        dst[(size_t)(n0 + nn) * 128 + k0_ + kk] = f2bf(tile[kk][nn]);
    }
}

// ---------------- MFMA zgemm: Z[m][u*4+g] = bf16( emb[x[m]] @ k0x + b0 ) ---------------
// GATE-INTERLEAVED output: lane's 4 gate preacts contiguous (uint2 read in lstm).
__global__ __launch_bounds__(256)
void zgemm_mf(const ushort_t* __restrict__ W1xT, const float* __restrict__ b0v,
              const float* __restrict__ emb, const int* __restrict__ idx,
              ushort_t* __restrict__ Zb)
{
    __shared__ ushort_t ash[64 * 136];
    const int tid = threadIdx.x;
    const int w = tid >> 6, lane = tid & 63;
    const int q = lane >> 4, n16 = lane & 15;
    const int m0 = blockIdx.x * 64;
    const int nbase = blockIdx.y * 256;

    for (int i = tid; i < 64 * 32; i += 256) {      // gather A: 64 rows x 128 k
        const int r_ = i >> 5, c4 = i & 31;
        const int m = m0 + r_;
        const int t = m >> 5, b = m & 31;
        const int id = idx[b * SS + t];
        const float4 v = ((const float4*)emb)[(size_t)id * 32 + c4];
        ushort_t o4[4] = { f2bf(v.x), f2bf(v.y), f2bf(v.z), f2bf(v.w) };
        *(uint2*)&ash[r_ * 136 + c4 * 4] = *(uint2*)o4;
    }
    __syncthreads();

    bf16x8 A[4];
#pragma unroll
    for (int kb = 0; kb < 4; kb++)
        A[kb] = *(const bf16x8*)&ash[(w * 16 + n16) * 136 + kb * 32 + q * 8];

#pragma unroll 1
    for (int nt = 0; nt < 16; nt++) {
        const int n = nbase + nt * 16 + n16;
        bf16x8 B[4];
#pragma unroll
        for (int kb = 0; kb < 4; kb++)
            B[kb] = *(const bf16x8*)&W1xT[(size_t)n * 128 + kb * 32 + q * 8];
        f32x4 C = (f32x4){0.f, 0.f, 0.f, 0.f};
#pragma unroll
        for (int kb = 0; kb < 4; kb++)
            C = MFMA(A[kb], B[kb], C);
        const float bv = b0v[n];
        const int g = n >> 8, u = n & 255;
#pragma unroll
        for (int r = 0; r < 4; r++)
            Zb[(size_t)(m0 + w * 16 + q * 4 + r) * 1024 + u * 4 + g] = f2bf(C[r] + bv);
    }
}

// ---------------- h-part weights -> fp8 K=128 fragment layout (R12-validated) ----------
__global__ __launch_bounds__(256)
void wf8k128(const float* __restrict__ src, uchar_t* __restrict__ dst)
{
    const int nt = blockIdx.x;             // 0..63
    const int t = threadIdx.x;
    const int kk = t >> 7, h = (t >> 6) & 1, l = t & 63;
    const int q = l >> 4, n16 = l & 15;
    const int col = (nt >> 4) * 256 + (nt & 15) * 16 + n16;
    uchar_t v[16];
#pragma unroll
    for (int j = 0; j < 16; j++) {
        const int k = kk * 128 + q * 32 + h * 16 + j;
        v[j] = f2fp8(src[(size_t)k * 1024 + col]);
    }
    *(uint4*)&dst[(((size_t)(nt * 2 + kk) * 2 + h) * 64 + l) * 16] = *(uint4*)v;
}

// ---------------- out_W -> fp8 K=128 fragment layout, V padded (R14-validated) ---------
__global__ __launch_bounds__(256)
void wtf8(const float* __restrict__ W, uchar_t* __restrict__ dst)
{
    const int nt = blockIdx.x;             // 0..627
    const int t = threadIdx.x;
    const int kk = t >> 7, h = (t >> 6) & 1, l = t & 63;
    const int q = l >> 4, n16 = l & 15;
    const int col = nt * 16 + n16;
    uchar_t v[16];
#pragma unroll
    for (int j = 0; j < 16; j++) {
        const int k = kk * 128 + q * 32 + h * 16 + j;
        v[j] = (col < VV) ? f2fp8(W[(size_t)k * VV + col]) : (uchar_t)0;
    }
    *(uint4*)&dst[(((size_t)(nt * 2 + kk) * 2 + h) * 64 + l) * 16] = *(uint4*)v;
}

// ---------------- fp32[256 x 1024] -> bf16 [1024][256] transpose (R6-validated) --------
__global__ __launch_bounds__(256)
void wtgen(const float* __restrict__ src, ushort_t* __restrict__ dst)
{
    __shared__ float tile[64][65];
    const int tid = threadIdx.x;
    const int n0 = blockIdx.x * 64, k0 = blockIdx.y * 64;
    for (int i = tid; i < 4096; i += 256) {
        const int kk = i >> 6, nn = i & 63;
        tile[kk][nn] = src[(size_t)(k0 + kk) * 1024 + n0 + nn];
    }
    __syncthreads();
    for (int i = tid; i < 4096; i += 256) {
        const int nn = i >> 6, kk = i & 63;
        dst[(size_t)(n0 + nn) * 256 + k0 + kk] = f2bf(tile[kk][nn]);
    }
}

__global__ __launch_bounds__(256)
void obset_kernel(const float* __restrict__ ob, float* __restrict__ obp)
{
    const int v = blockIdx.x * 256 + threadIdx.x;
    if (v < VPAD) obp[v] = (v < VV) ? ob[v] : -INFINITY;
}

// ---------------- batch-parallel LSTM, K=128 fp8, 8 waves (R16 structure) ----------------
// z now gate-interleaved: ONE uint2 load per lane per step (was 4 scattered ushorts).
__global__ __launch_bounds__(512, 2)
void lstm_mx8(const uchar_t* __restrict__ Wsw, const ushort_t* __restrict__ zin,
              const int* __restrict__ lens, ushort_t* __restrict__ outp,
              uchar_t* __restrict__ hf8)
{
    __shared__ uchar_t Bl[98304];      // 8 waves x 3 tiles x 4 KB
    __shared__ uchar_t h8[2][256];
    const int tid = threadIdx.x;
    const int w = tid >> 6, lane = tid & 63;
    const int q = lane >> 4, n16 = lane & 15;
    const int b = blockIdx.x;
    const int len = lens[b];
    const int jown = q >> 1;
    const int unit = w * 32 + jown * 16 + n16;

    // LDS staging: wave-local tiles {(0,1),(1,1),(2,1)}
#pragma unroll
    for (int li = 0; li < 3; li++) {
        const int nt = li * 16 + w * 2 + 1;
#pragma unroll
        for (int fh = 0; fh < 4; fh++) {
            const size_t s = (((size_t)nt * 4 + fh) * 64 + lane) * 16;
            const size_t d = (((size_t)(w * 3 + li) * 4 + fh) * 64 + lane) * 16;
            *(uint4*)&Bl[d] = *(const uint4*)&Wsw[s];
        }
    }
    // VGPR tiles {(g,0)}
    i32x8 Bv[4][2];
#pragma unroll
    for (int g = 0; g < 4; g++) {
        const int nt = g * 16 + w * 2;
#pragma unroll
        for (int kk = 0; kk < 2; kk++)
            Bv[g][kk] = ldfrag(&Wsw[(size_t)nt * 4096 + kk * 2048], lane);
    }
    if (tid < 256) { h8[0][tid] = 0; h8[1][tid] = 0; }
    float c = 0.f;
    __syncthreads();

    const uchar_t* Lb0 = &Bl[(size_t)(w * 3) * 4096];   // wave's LDS region

    for (int t = 0; t < SS; t++) {
        if (t >= len) {                // uniform: zero remaining rows, done
            uint4 zz; zz.x = zz.y = zz.z = zz.w = 0u;
            const int nseg = (SS - t) * 32;
            for (int i = tid; i < nseg; i += 512) {
                const int tt = t + (i >> 5), seg = i & 31;
                *(uint4*)&outp[((size_t)tt * 32 + b) * 256 + seg * 8] = zz;
            }
            if (hf8) {
                const int nseg8 = (SS - t) * 16;
                for (int i = tid; i < nseg8; i += 512) {
                    const int tt = t + (i >> 4), seg = i & 15;
                    *(uint4*)&hf8[((size_t)tt * 32 + b) * 256 + seg * 16] = zz;
                }
            }
            break;
        }
        const size_t row = (size_t)t * 32 + b;
        // streamed tile (3,1) — issue first, consume last
        i32x8 St[2];
        {
            const int nt = 3 * 16 + w * 2 + 1;
#pragma unroll
            for (int kk = 0; kk < 2; kk++)
                St[kk] = ldfrag(&Wsw[(size_t)nt * 4096 + kk * 2048], lane);
        }
        ushort_t z4[4];                // gate-interleaved: one 8-B load
        *(uint2*)z4 = *(const uint2*)&zin[row * 1024 + unit * 4];

        const int rd = t & 1, wr = rd ^ 1;
        i32x8 Af0, Af1;                // A: rows identical (quad-broadcast from h8)
        ((uint4*)&Af0)[0] = *(const uint4*)&h8[rd][q * 32];
        ((uint4*)&Af0)[1] = *(const uint4*)&h8[rd][q * 32 + 16];
        ((uint4*)&Af1)[0] = *(const uint4*)&h8[rd][128 + q * 32];
        ((uint4*)&Af1)[1] = *(const uint4*)&h8[rd][128 + q * 32 + 16];

        float gvv[4];
#pragma unroll
        for (int g = 0; g < 4; g++) {
            f32x4 C0 = (f32x4){0.f,0.f,0.f,0.f}, C1 = (f32x4){0.f,0.f,0.f,0.f};
            C0 = MFMAS(Af0, Bv[g][0], C0);         // j=0 from VGPR
            C0 = MFMAS(Af1, Bv[g][1], C0);
            if (g < 3) {               // (g,1) from LDS li = g
                const uchar_t* p = Lb0 + (size_t)g * 4096;
                C1 = MFMAS(Af0, ldfrag(p, lane), C1);
                C1 = MFMAS(Af1, ldfrag(p + 2048, lane), C1);
            } else {                   // (3,1) streamed
                C1 = MFMAS(Af0, St[0], C1);
                C1 = MFMAS(Af1, St[1], C1);
            }
            gvv[g] = jown ? C1[0] : C0[0];   // rows identical; col = n16 of owned tile
        }
        {
            const float zi = bf2f(z4[0]) + gvv[0];
            const float zg = bf2f(z4[1]) + gvv[1];
            const float zf = bf2f(z4[2]) + gvv[2];
            const float zo = bf2f(z4[3]) + gvv[3];
            const float cn = sigf(zf + 1.0f) * c + sigf(zi) * tanhf_(zg);
            const float hn = sigf(zo) * tanhf_(cn);
            c = cn;
            const uchar_t h8v = f2fp8(hn);
            h8[wr][unit] = h8v;                       // dup lanes write same value
            outp[row * 256 + unit] = f2bf(hn);
            if (hf8) hf8[row * 256 + unit] = h8v;
        }
        __syncthreads();               // h8[wr] complete + visible for next step
    }
}

// ---------------- layer-2 x-part GEMM + b1, gate-interleaved out, LDS-staged A ----------
__global__ __launch_bounds__(512, 2)
void xgemm2p(const ushort_t* __restrict__ out1, const ushort_t* __restrict__ W2x,
             const float* __restrict__ b1v, ushort_t* __restrict__ Xp)
{
    __shared__ ushort_t ash[128 * 264];        // 128 rows, padded stride (ce-validated)
    const int tid = threadIdx.x;
    const int w = tid >> 6, lane = tid & 63;
    const int q = lane >> 4, n16 = lane & 15;
    const int m0 = blockIdx.x * 128;           // 4 timesteps x 32 batch

    for (int i = tid; i < 128 * 32; i += 512) {
        const int r_ = i >> 5, s_ = i & 31;
        *(uint4*)&ash[r_ * 264 + s_ * 8] = *(const uint4*)&out1[(size_t)(m0 + r_) * 256 + s_ * 8];
    }
    __syncthreads();

#pragma unroll 1
    for (int i = 0; i < 8; i++) {
        const int n = (w * 8 + i) * 16 + n16;
        bf16x8 Bfr[8];
#pragma unroll
        for (int kb = 0; kb < 8; kb++)
            Bfr[kb] = *(const bf16x8*)&W2x[(size_t)n * 256 + kb * 32 + q * 8];
        const float bval = b1v[n];
        const int g = n >> 8, u = n & 255;
        f32x4 Cc[8];
#pragma unroll
        for (int mt = 0; mt < 8; mt++) {
            Cc[mt] = (f32x4){0.f, 0.f, 0.f, 0.f};
            bf16x8 Af[8];
#pragma unroll
            for (int kb = 0; kb < 8; kb++)
                Af[kb] = *(const bf16x8*)&ash[(mt * 16 + n16) * 264 + kb * 32 + q * 8];
#pragma unroll
            for (int kb = 0; kb < 8; kb++)
                Cc[mt] = MFMA(Af[kb], Bfr[kb], Cc[mt]);
        }
#pragma unroll
        for (int mt = 0; mt < 8; mt++)
#pragma unroll
            for (int r = 0; r < 4; r++) {
                const int rrow = m0 + mt * 16 + q * 4 + r;
                Xp[(size_t)rrow * 1024 + u * 4 + g] = f2bf(Cc[mt][r] + bval);
            }
    }
}

// ---------------- fp8 K=128 fused projection + CE (R14-validated) ----------------
__global__ __launch_bounds__(256, 1)
void ce_kernel(const uchar_t* __restrict__ hf8, const uchar_t* __restrict__ Wt8,
               const float* __restrict__ obp, const int* __restrict__ y,
               const int* __restrict__ lens, float* __restrict__ out)
{
    __shared__ float lsw[4][64];
    __shared__ float tgt64[64];
    const int tid = threadIdx.x;
    const int w = tid >> 6, lane = tid & 63;
    const int q = lane >> 4, n16 = lane & 15;
    const int m0 = blockIdx.x * 64;

    if (tid < 64) tgt64[tid] = 0.f;

    i32x8 A8[4][2];
#pragma unroll
    for (int mt = 0; mt < 4; mt++) {
        const size_t rbase = (size_t)(m0 + mt * 16 + n16) * 256;
#pragma unroll
        for (int kk = 0; kk < 2; kk++) {
            ((uint4*)&A8[mt][kk])[0] = *(const uint4*)&hf8[rbase + kk * 128 + q * 32];
            ((uint4*)&A8[mt][kk])[1] = *(const uint4*)&hf8[rbase + kk * 128 + q * 32 + 16];
        }
    }
    int yv[16];
#pragma unroll
    for (int mt = 0; mt < 4; mt++)
#pragma unroll
        for (int r = 0; r < 4; r++) {
            const int m = m0 + mt * 16 + q * 4 + r;
            yv[mt * 4 + r] = y[(m & 31) * SS + (m >> 5)];
        }
    float lsum[16];
#pragma unroll
    for (int i = 0; i < 16; i++) lsum[i] = 0.f;
    __syncthreads();                   // tgt64 init visible

    for (int tile = 0; tile < 157; tile++) {
        const int nt = w * 157 + tile;
        const int n = nt * 16 + n16;
        const i32x8 B0 = ldfrag(&Wt8[(size_t)(nt * 2 + 0) * 2048], lane);
        const i32x8 B1 = ldfrag(&Wt8[(size_t)(nt * 2 + 1) * 2048], lane);
        const float obv = obp[n];
        f32x4 C[4];
#pragma unroll
        for (int mt = 0; mt < 4; mt++) {
            C[mt] = (f32x4){0.f, 0.f, 0.f, 0.f};
            C[mt] = MFMAS(A8[mt][0], B0, C[mt]);
            C[mt] = MFMAS(A8[mt][1], B1, C[mt]);
        }
#pragma unroll
        for (int mt = 0; mt < 4; mt++)
#pragma unroll
            for (int r = 0; r < 4; r++) {
                const float sc = C[mt][r] + obv;     // -inf on padded cols
                if (n == yv[mt * 4 + r]) tgt64[mt * 16 + q * 4 + r] = sc;
                lsum[mt * 4 + r] += __expf(sc - 16.0f);
            }
    }
#pragma unroll
    for (int i = 0; i < 16; i++) {
        float v = lsum[i];
        v += __shfl_xor(v, 1, 16); v += __shfl_xor(v, 2, 16);
        v += __shfl_xor(v, 4, 16); v += __shfl_xor(v, 8, 16);
        lsum[i] = v;
    }
    if (n16 == 0)
#pragma unroll
        for (int i = 0; i < 16; i++)
            lsw[w][(i >> 2) * 16 + q * 4 + (i & 3)] = lsum[i];
    __syncthreads();

    if (tid < 64) {
        const float l = lsw[0][tid] + lsw[1][tid] + lsw[2][tid] + lsw[3][tid];
        const float lse = 16.0f + __logf(l);
        const int m = m0 + tid;
        const int tt = m >> 5, bb = m & 31;
        const int yvv = y[bb * SS + tt];
        float local = (yvv != 0) ? (lse - tgt64[tid]) / (32.0f * (float)lens[bb]) : 0.f;
        for (int off = 1; off < 64; off <<= 1) local += __shfl_xor(local, off, 64);
        if (tid == 0) atomicAdd(out, local);
    }
}

extern "C" void kernel_launch(void* const* d_in, const int* in_sizes, int n_in,
                              void* d_out, int out_size, void* d_ws, size_t ws_size,
                              hipStream_t stream)
{
    const int*   input_x = (const int*)  d_in[0];
    const int*   input_y = (const int*)  d_in[1];
    const int*   lens    = (const int*)  d_in[2];
    const float* emb_W   = (const float*)d_in[3];
    const float* k0      = (const float*)d_in[4];
    const float* b0      = (const float*)d_in[5];
    const float* k1      = (const float*)d_in[6];
    const float* b1      = (const float*)d_in[7];
    const float* out_W   = (const float*)d_in[8];
    const float* out_b   = (const float*)d_in[9];
    float* out = (float*)d_out;

    char* p = (char*)d_ws;
    ushort_t* Zb   = (ushort_t*)p;  p += (size_t)NROWS * 1024 * 2;    // 33.55 MB
    ushort_t* Xp   = (ushort_t*)p;  p += (size_t)NROWS * 1024 * 2;    // 33.55 MB
    ushort_t* out1 = (ushort_t*)p;  p += (size_t)NROWS * 256 * 2;     // 8.39 MB
    ushort_t* h2bf = (ushort_t*)p;  p += (size_t)NROWS * 256 * 2;     // 8.39 MB
    uchar_t*  h2f8 = (uchar_t*)p;   p += (size_t)NROWS * 256;         // 4.19 MB
    uchar_t*  Wsw1 = (uchar_t*)p;   p += (size_t)1024 * 256;          // 256 KB
    uchar_t*  Wsw2 = (uchar_t*)p;   p += (size_t)1024 * 256;          // 256 KB
    ushort_t* W2x  = (ushort_t*)p;  p += (size_t)1024 * 256 * 2;      // 512 KB
    ushort_t* W1xT = (ushort_t*)p;  p += (size_t)1024 * 128 * 2;      // 256 KB
    uchar_t*  Wt8  = (uchar_t*)p;   p += (size_t)NT8 * 4096;          // 2.57 MB
    float*    obp  = (float*)p;     p += (size_t)VPAD * 4;

    hipMemsetAsync(d_out, 0, sizeof(float), stream);

    wtx<<<dim3(16, 2), 256, 0, stream>>>(k0, W1xT);                  // k0 x-part bf16^T
    zgemm_mf<<<dim3(256, 4), 256, 0, stream>>>(W1xT, b0, emb_W, input_x, Zb);
    wf8k128<<<64, 256, 0, stream>>>(k0 + (size_t)EE * 1024, Wsw1);   // L1 h-part fp8 K128
    wf8k128<<<64, 256, 0, stream>>>(k1 + (size_t)HH * 1024, Wsw2);   // L2 h-part fp8 K128
    wtgen<<<dim3(16, 4), 256, 0, stream>>>(k1, W2x);                 // L2 x-part bf16
    wtf8<<<NT8, 256, 0, stream>>>(out_W, Wt8);                       // out_W fp8 K128
    obset_kernel<<<(VPAD + 255) / 256, 256, 0, stream>>>(out_b, obp);

    lstm_mx8<<<BB, 512, 0, stream>>>(Wsw1, Zb, lens, out1, nullptr);
    xgemm2p<<<128, 512, 0, stream>>>(out1, W2x, b1, Xp);
    lstm_mx8<<<BB, 512, 0, stream>>>(Wsw2, Xp, lens, h2bf, h2f8);
    ce_kernel<<<NROWS / 64, 256, 0, stream>>>(h2f8, Wt8, obp, input_y, lens, out);
}

// Round 18
// 1379.730 us; speedup vs baseline: 1.2137x; 1.2137x over previous
//
#include <hip/hip_runtime.h>
#include <hip/hip_fp8.h>
#include <cmath>

#define SS 512
#define BB 32
#define EE 128
#define HH 256
#define VV 10000
#define NROWS (SS*BB)   // 16384
#define VPAD 10048
#define NT8 (VPAD/16)   // 628 fp8 B-tiles

typedef unsigned short ushort_t;
typedef unsigned char uchar_t;
typedef __attribute__((ext_vector_type(8))) short bf16x8;
typedef __attribute__((ext_vector_type(8))) int i32x8;
typedef __attribute__((ext_vector_type(4))) float f32x4;

#define MFMA(a,b,c)  __builtin_amdgcn_mfma_f32_16x16x32_bf16((a),(b),(c),0,0,0)
#define MFMAS(a,b,c) __builtin_amdgcn_mfma_scale_f32_16x16x128_f8f6f4((a),(b),(c),0,0,0,0x7F7F7F7F,0,0x7F7F7F7F)

__device__ __forceinline__ ushort_t f2bf(float x) {
    unsigned u = __float_as_uint(x);
    u = (u + 0x7FFFu + ((u >> 16) & 1u)) >> 16;   // RNE
    return (ushort_t)u;
}
__device__ __forceinline__ float bf2f(ushort_t h) {
    return __uint_as_float(((unsigned)h) << 16);
}
__device__ __forceinline__ uchar_t f2fp8(float x) {
    __hip_fp8_e4m3 t(x);                           // OCP e4m3
    return (uchar_t)t.__x;
}
__device__ __forceinline__ float sigf(float x) { return 1.0f / (1.0f + __expf(-x)); }
__device__ __forceinline__ float tanhf_(float x) { return 1.0f - 2.0f / (__expf(2.0f * x) + 1.0f); }

__device__ __forceinline__ i32x8 ldfrag(const uchar_t* base, int lane) {
    i32x8 r;
    ((uint4*)&r)[0] = *(const uint4*)(base + lane * 16);
    ((uint4*)&r)[1] = *(const uint4*)(base + 1024 + lane * 16);
    return r;
}

__device__ __forceinline__ void pollc(unsigned* p, unsigned target) {
    int it = 0;
    while (__hip_atomic_load(p, __ATOMIC_RELAXED, __HIP_MEMORY_SCOPE_AGENT) < target) {
        __builtin_amdgcn_s_sleep(4);
        if (++it > 50000000) break;    // anti-hang cap
    }
}
__device__ __forceinline__ void reladd(unsigned* p) {
    __hip_atomic_fetch_add(p, 1u, __ATOMIC_RELEASE, __HIP_MEMORY_SCOPE_AGENT);
}

// ---------------- k0 x-part transpose (R16-validated) ----------------
__global__ __launch_bounds__(256)
void wtx(const float* __restrict__ src, ushort_t* __restrict__ dst)
{
    __shared__ float tile[64][65];
    const int tid = threadIdx.x;
    const int n0 = blockIdx.x * 64, k0_ = blockIdx.y * 64;
    for (int i = tid; i < 4096; i += 256) {
        const int kk = i >> 6, nn = i & 63;
        tile[kk][nn] = src[(size_t)(k0_ + kk) * 1024 + n0 + nn];
    }
    __syncthreads();
    for (int i = tid; i < 4096; i += 256) {
        const int nn = i >> 6, kk = i & 63;
        dst[(size_t)(n0 + nn) * 128 + k0_ + kk] = f2bf(tile[kk][nn]);
    }
}

// ---------------- MFMA zgemm, gate-interleaved out (R17-validated) ----------------
__global__ __launch_bounds__(256)
void zgemm_mf(const ushort_t* __restrict__ W1xT, const float* __restrict__ b0v,
              const float* __restrict__ emb, const int* __restrict__ idx,
              ushort_t* __restrict__ Zb)
{
    __shared__ ushort_t ash[64 * 136];
    const int tid = threadIdx.x;
    const int w = tid >> 6, lane = tid & 63;
    const int q = lane >> 4, n16 = lane & 15;
    const int m0 = blockIdx.x * 64;
    const int nbase = blockIdx.y * 256;

    for (int i = tid; i < 64 * 32; i += 256) {
        const int r_ = i >> 5, c4 = i & 31;
        const int m = m0 + r_;
        const int t = m >> 5, b = m & 31;
        const int id = idx[b * SS + t];
        const float4 v = ((const float4*)emb)[(size_t)id * 32 + c4];
        ushort_t o4[4] = { f2bf(v.x), f2bf(v.y), f2bf(v.z), f2bf(v.w) };
        *(uint2*)&ash[r_ * 136 + c4 * 4] = *(uint2*)o4;
    }
    __syncthreads();

    bf16x8 A[4];
#pragma unroll
    for (int kb = 0; kb < 4; kb++)
        A[kb] = *(const bf16x8*)&ash[(w * 16 + n16) * 136 + kb * 32 + q * 8];

#pragma unroll 1
    for (int nt = 0; nt < 16; nt++) {
        const int n = nbase + nt * 16 + n16;
        bf16x8 B[4];
#pragma unroll
        for (int kb = 0; kb < 4; kb++)
            B[kb] = *(const bf16x8*)&W1xT[(size_t)n * 128 + kb * 32 + q * 8];
        f32x4 C = (f32x4){0.f, 0.f, 0.f, 0.f};
#pragma unroll
        for (int kb = 0; kb < 4; kb++)
            C = MFMA(A[kb], B[kb], C);
        const float bv = b0v[n];
        const int g = n >> 8, u = n & 255;
#pragma unroll
        for (int r = 0; r < 4; r++)
            Zb[(size_t)(m0 + w * 16 + q * 4 + r) * 1024 + u * 4 + g] = f2bf(C[r] + bv);
    }
}

// ---------------- h-part weights -> fp8 K=128 frag layout (R12-validated) ----------
__global__ __launch_bounds__(256)
void wf8k128(const float* __restrict__ src, uchar_t* __restrict__ dst)
{
    const int nt = blockIdx.x;
    const int t = threadIdx.x;
    const int kk = t >> 7, h = (t >> 6) & 1, l = t & 63;
    const int q = l >> 4, n16 = l & 15;
    const int col = (nt >> 4) * 256 + (nt & 15) * 16 + n16;
    uchar_t v[16];
#pragma unroll
    for (int j = 0; j < 16; j++) {
        const int k = kk * 128 + q * 32 + h * 16 + j;
        v[j] = f2fp8(src[(size_t)k * 1024 + col]);
    }
    *(uint4*)&dst[(((size_t)(nt * 2 + kk) * 2 + h) * 64 + l) * 16] = *(uint4*)v;
}

// ---------------- out_W -> fp8 K=128 frag layout (R14-validated) ----------
__global__ __launch_bounds__(256)
void wtf8(const float* __restrict__ W, uchar_t* __restrict__ dst)
{
    const int nt = blockIdx.x;
    const int t = threadIdx.x;
    const int kk = t >> 7, h = (t >> 6) & 1, l = t & 63;
    const int q = l >> 4, n16 = l & 15;
    const int col = nt * 16 + n16;
    uchar_t v[16];
#pragma unroll
    for (int j = 0; j < 16; j++) {
        const int k = kk * 128 + q * 32 + h * 16 + j;
        v[j] = (col < VV) ? f2fp8(W[(size_t)k * VV + col]) : (uchar_t)0;
    }
    *(uint4*)&dst[(((size_t)(nt * 2 + kk) * 2 + h) * 64 + l) * 16] = *(uint4*)v;
}

// ---------------- fp32[256 x 1024] -> bf16 [1024][256] transpose (R6-validated) ------
__global__ __launch_bounds__(256)
void wtgen(const float* __restrict__ src, ushort_t* __restrict__ dst)
{
    __shared__ float tile[64][65];
    const int tid = threadIdx.x;
    const int n0 = blockIdx.x * 64, k0 = blockIdx.y * 64;
    for (int i = tid; i < 4096; i += 256) {
        const int kk = i >> 6, nn = i & 63;
        tile[kk][nn] = src[(size_t)(k0 + kk) * 1024 + n0 + nn];
    }
    __syncthreads();
    for (int i = tid; i < 4096; i += 256) {
        const int nn = i >> 6, kk = i & 63;
        dst[(size_t)(n0 + nn) * 256 + k0 + kk] = f2bf(tile[kk][nn]);
    }
}

__global__ __launch_bounds__(256)
void obset_kernel(const float* __restrict__ ob, float* __restrict__ obp)
{
    const int v = blockIdx.x * 256 + threadIdx.x;
    if (v < VPAD) obp[v] = (v < VV) ? ob[v] : -INFINITY;
}

// ---------------- LSTM recurrence role (R17 structure + chunk flags) ----------------
__device__ __forceinline__ void lstm_role(
    uchar_t* Bl, uchar_t* h8buf,
    const uchar_t* __restrict__ Wsw, const ushort_t* __restrict__ zin,
    const int* __restrict__ lens, ushort_t* __restrict__ outp,
    uchar_t* __restrict__ hf8,
    unsigned* prog1, unsigned* xflag, unsigned* h2prog,
    int b, bool isL1)
{
    uchar_t (*h8)[256] = (uchar_t (*)[256])h8buf;
    const int tid = threadIdx.x;
    const int w = tid >> 6, lane = tid & 63;
    const int q = lane >> 4, n16 = lane & 15;
    const int len = lens[b];
    const int jown = q >> 1;
    const int unit = w * 32 + jown * 16 + n16;

#pragma unroll
    for (int li = 0; li < 3; li++) {
        const int nt = li * 16 + w * 2 + 1;
#pragma unroll
        for (int fh = 0; fh < 4; fh++) {
            const size_t s = (((size_t)nt * 4 + fh) * 64 + lane) * 16;
            const size_t d = (((size_t)(w * 3 + li) * 4 + fh) * 64 + lane) * 16;
            *(uint4*)&Bl[d] = *(const uint4*)&Wsw[s];
        }
    }
    i32x8 Bv[4][2];
#pragma unroll
    for (int g = 0; g < 4; g++) {
        const int nt = g * 16 + w * 2;
#pragma unroll
        for (int kk = 0; kk < 2; kk++)
            Bv[g][kk] = ldfrag(&Wsw[(size_t)nt * 4096 + kk * 2048], lane);
    }
    if (tid < 256) { h8[0][tid] = 0; h8[1][tid] = 0; }
    float c = 0.f;
    __syncthreads();

    const uchar_t* Lb0 = &Bl[(size_t)(w * 3) * 4096];

    for (int t = 0; t < SS; t++) {
        if (t >= len) {                // uniform early exit: zero rest, release rest
            uint4 zz; zz.x = zz.y = zz.z = zz.w = 0u;
            if (outp) {
                const int nseg = (SS - t) * 32;
                for (int i = tid; i < nseg; i += 512) {
                    const int tt = t + (i >> 5), seg = i & 31;
                    *(uint4*)&outp[((size_t)tt * 32 + b) * 256 + seg * 8] = zz;
                }
            }
            if (hf8) {
                const int nseg8 = (SS - t) * 16;
                for (int i = tid; i < nseg8; i += 512) {
                    const int tt = t + (i >> 4), seg = i & 15;
                    *(uint4*)&hf8[((size_t)tt * 32 + b) * 256 + seg * 16] = zz;
                }
            }
            __syncthreads();           // drain zero-fill stores
            if (tid == 0) {
                if (isL1) for (int cc = t >> 5; cc < 16; cc++) reladd(&prog1[cc]);
                else      for (int cc = t >> 3; cc < 64; cc++) reladd(&h2prog[cc]);
            }
            break;
        }
        if (!isL1 && (t & 7) == 0) {   // consume xgemm chunk t>>3
            if (tid == 0) pollc(&xflag[t >> 3], 1u);
            __syncthreads();
            __builtin_amdgcn_fence(__ATOMIC_ACQUIRE, "agent");
        }
        const size_t row = (size_t)t * 32 + b;
        i32x8 St[2];                   // streamed tile (3,1)
        {
            const int nt = 3 * 16 + w * 2 + 1;
#pragma unroll
            for (int kk = 0; kk < 2; kk++)
                St[kk] = ldfrag(&Wsw[(size_t)nt * 4096 + kk * 2048], lane);
        }
        ushort_t z4[4];
        *(uint2*)z4 = *(const uint2*)&zin[row * 1024 + unit * 4];

        const int rd = t & 1, wr = rd ^ 1;
        i32x8 Af0, Af1;
        ((uint4*)&Af0)[0] = *(const uint4*)&h8[rd][q * 32];
        ((uint4*)&Af0)[1] = *(const uint4*)&h8[rd][q * 32 + 16];
        ((uint4*)&Af1)[0] = *(const uint4*)&h8[rd][128 + q * 32];
        ((uint4*)&Af1)[1] = *(const uint4*)&h8[rd][128 + q * 32 + 16];

        float gvv[4];
#pragma unroll
        for (int g = 0; g < 4; g++) {
            f32x4 C0 = (f32x4){0.f,0.f,0.f,0.f}, C1 = (f32x4){0.f,0.f,0.f,0.f};
            C0 = MFMAS(Af0, Bv[g][0], C0);
            C0 = MFMAS(Af1, Bv[g][1], C0);
            if (g < 3) {
                const uchar_t* p = Lb0 + (size_t)g * 4096;
                C1 = MFMAS(Af0, ldfrag(p, lane), C1);
                C1 = MFMAS(Af1, ldfrag(p + 2048, lane), C1);
            } else {
                C1 = MFMAS(Af0, St[0], C1);
                C1 = MFMAS(Af1, St[1], C1);
            }
            gvv[g] = jown ? C1[0] : C0[0];
        }
        {
            const float zi = bf2f(z4[0]) + gvv[0];
            const float zg = bf2f(z4[1]) + gvv[1];
            const float zf = bf2f(z4[2]) + gvv[2];
            const float zo = bf2f(z4[3]) + gvv[3];
            const float cn = sigf(zf + 1.0f) * c + sigf(zi) * tanhf_(zg);
            const float hn = sigf(zo) * tanhf_(cn);
            c = cn;
            const uchar_t h8v = f2fp8(hn);
            h8[wr][unit] = h8v;
            if (outp) outp[row * 256 + unit] = f2bf(hn);
            if (hf8) hf8[row * 256 + unit] = h8v;
        }
        __syncthreads();               // h8[wr] ready + all stores drained
        if (tid == 0) {
            if (isL1) { if (((t + 1) & 31) == 0) reladd(&prog1[t >> 5]); }
            else      { if (((t + 1) & 7)  == 0) reladd(&h2prog[t >> 3]); }
        }
    }
}

// ---------------- fused pipeline kernel: 256 co-resident blocks ----------------
// blk 0..31: lstm1 | 32..95: xgemm (8 t each) | 96..127: lstm2 | 128..255: ce.
__global__ __launch_bounds__(512, 1)
void pipe_kernel(const uchar_t* __restrict__ Wsw1, const uchar_t* __restrict__ Wsw2,
                 const ushort_t* __restrict__ W2x, const float* __restrict__ b1v,
                 const int* __restrict__ lens, const ushort_t* __restrict__ Zb,
                 ushort_t* __restrict__ out1, ushort_t* __restrict__ Xp,
                 uchar_t* __restrict__ hf8, const uchar_t* __restrict__ Wt8,
                 const float* __restrict__ obp, const int* __restrict__ y,
                 float* __restrict__ out,
                 unsigned* __restrict__ prog1, unsigned* __restrict__ xflag,
                 unsigned* __restrict__ h2prog)
{
    __shared__ uchar_t smem[98816];
    const int tid = threadIdx.x;
    const int blk = blockIdx.x;
    const int w = tid >> 6, lane = tid & 63;
    const int q = lane >> 4, n16 = lane & 15;

    if (blk < 32) {
        lstm_role(smem, smem + 98304, Wsw1, Zb, lens, out1, nullptr,
                  prog1, xflag, h2prog, blk, true);
    } else if (blk < 96) {
        // ---------------- xgemm role: timesteps [b2*8, b2*8+8) ----------------
        ushort_t* ash = (ushort_t*)smem;           // 128 x 264
        const int b2 = blk - 32;
        if (tid == 0) pollc(&prog1[b2 >> 2], 32u);
        __syncthreads();
        __builtin_amdgcn_fence(__ATOMIC_ACQUIRE, "agent");
#pragma unroll 1
        for (int half = 0; half < 2; half++) {
            const int m0 = b2 * 256 + half * 128;
            if (half) __syncthreads();             // protect ash overwrite
            for (int i = tid; i < 128 * 32; i += 512) {
                const int r_ = i >> 5, s_ = i & 31;
                *(uint4*)&ash[r_ * 264 + s_ * 8] =
                    *(const uint4*)&out1[(size_t)(m0 + r_) * 256 + s_ * 8];
            }
            __syncthreads();
#pragma unroll 1
            for (int i = 0; i < 8; i++) {
                const int n = (w * 8 + i) * 16 + n16;
                bf16x8 Bfr[8];
#pragma unroll
                for (int kb = 0; kb < 8; kb++)
                    Bfr[kb] = *(const bf16x8*)&W2x[(size_t)n * 256 + kb * 32 + q * 8];
                const float bval = b1v[n];
                const int g = n >> 8, u = n & 255;
                f32x4 Cc[8];
#pragma unroll
                for (int mt = 0; mt < 8; mt++) {
                    Cc[mt] = (f32x4){0.f, 0.f, 0.f, 0.f};
                    bf16x8 Af[8];
#pragma unroll
                    for (int kb = 0; kb < 8; kb++)
                        Af[kb] = *(const bf16x8*)&ash[(mt * 16 + n16) * 264 + kb * 32 + q * 8];
#pragma unroll
                    for (int kb = 0; kb < 8; kb++)
                        Cc[mt] = MFMA(Af[kb], Bfr[kb], Cc[mt]);
                }
#pragma unroll
                for (int mt = 0; mt < 8; mt++)
#pragma unroll
                    for (int r = 0; r < 4; r++) {
                        const int rrow = m0 + mt * 16 + q * 4 + r;
                        Xp[(size_t)rrow * 1024 + u * 4 + g] = f2bf(Cc[mt][r] + bval);
                    }
            }
        }
        __syncthreads();               // drain Xp stores
        if (tid == 0)
            __hip_atomic_store(&xflag[b2], 1u, __ATOMIC_RELEASE, __HIP_MEMORY_SCOPE_AGENT);
    } else if (blk < 128) {
        lstm_role(smem, smem + 98304, Wsw2, Xp, lens, nullptr, hf8,
                  prog1, xflag, h2prog, blk - 96, false);
    } else {
        // ---------------- ce role: rows [cb*128, +128) ----------------
        float* lsw = (float*)smem;                 // [4][64]
        float* tgt64 = (float*)(smem + 1024);      // [64]
        const int cb = blk - 128;
        if (tid == 0) pollc(&h2prog[cb >> 1], 32u);
        __syncthreads();
        __builtin_amdgcn_fence(__ATOMIC_ACQUIRE, "agent");
#pragma unroll 1
        for (int half = 0; half < 2; half++) {
            const int m0 = cb * 128 + half * 64;
            __syncthreads();           // protect tgt64/lsw reuse
            if (tid < 64) tgt64[tid] = 0.f;
            i32x8 A8[4][2];
            int yv[16];
            float lsum[16];
            if (tid < 256) {
#pragma unroll
                for (int mt = 0; mt < 4; mt++) {
                    const size_t rbase = (size_t)(m0 + mt * 16 + n16) * 256;
#pragma unroll
                    for (int kk = 0; kk < 2; kk++) {
                        ((uint4*)&A8[mt][kk])[0] = *(const uint4*)&hf8[rbase + kk * 128 + q * 32];
                        ((uint4*)&A8[mt][kk])[1] = *(const uint4*)&hf8[rbase + kk * 128 + q * 32 + 16];
                    }
                }
#pragma unroll
                for (int mt = 0; mt < 4; mt++)
#pragma unroll
                    for (int r = 0; r < 4; r++) {
                        const int m = m0 + mt * 16 + q * 4 + r;
                        yv[mt * 4 + r] = y[(m & 31) * SS + (m >> 5)];
                    }
#pragma unroll
                for (int i = 0; i < 16; i++) lsum[i] = 0.f;
            }
            __syncthreads();           // tgt64 init visible
            if (tid < 256) {
                for (int tile = 0; tile < 157; tile++) {
                    const int nt = w * 157 + tile;
                    const int n = nt * 16 + n16;
                    const i32x8 B0 = ldfrag(&Wt8[(size_t)(nt * 2 + 0) * 2048], lane);
                    const i32x8 B1 = ldfrag(&Wt8[(size_t)(nt * 2 + 1) * 2048], lane);
                    const float obv = obp[n];
                    f32x4 C[4];
#pragma unroll
                    for (int mt = 0; mt < 4; mt++) {
                        C[mt] = (f32x4){0.f, 0.f, 0.f, 0.f};
                        C[mt] = MFMAS(A8[mt][0], B0, C[mt]);
                        C[mt] = MFMAS(A8[mt][1], B1, C[mt]);
                    }
#pragma unroll
                    for (int mt = 0; mt < 4; mt++)
#pragma unroll
                        for (int r = 0; r < 4; r++) {
                            const float sc = C[mt][r] + obv;
                            if (n == yv[mt * 4 + r]) tgt64[mt * 16 + q * 4 + r] = sc;
                            lsum[mt * 4 + r] += __expf(sc - 16.0f);
                        }
                }
#pragma unroll
                for (int i = 0; i < 16; i++) {
                    float v = lsum[i];
                    v += __shfl_xor(v, 1, 16); v += __shfl_xor(v, 2, 16);
                    v += __shfl_xor(v, 4, 16); v += __shfl_xor(v, 8, 16);
                    lsum[i] = v;
                }
                if (n16 == 0)
#pragma unroll
                    for (int i = 0; i < 16; i++)
                        lsw[w * 64 + (i >> 2) * 16 + q * 4 + (i & 3)] = lsum[i];
            }
            __syncthreads();
            if (tid < 64) {
                const float l = lsw[tid] + lsw[64 + tid] + lsw[128 + tid] + lsw[192 + tid];
                const float lse = 16.0f + __logf(l);
                const int m = m0 + tid;
                const int tt = m >> 5, bb = m & 31;
                const int yvv = y[bb * SS + tt];
                float local = (yvv != 0) ? (lse - tgt64[tid]) / (32.0f * (float)lens[bb]) : 0.f;
                for (int off = 1; off < 64; off <<= 1) local += __shfl_xor(local, off, 64);
                if (tid == 0) atomicAdd(out, local);
            }
        }
    }
}

extern "C" void kernel_launch(void* const* d_in, const int* in_sizes, int n_in,
                              void* d_out, int out_size, void* d_ws, size_t ws_size,
                              hipStream_t stream)
{
    const int*   input_x = (const int*)  d_in[0];
    const int*   input_y = (const int*)  d_in[1];
    const int*   lens    = (const int*)  d_in[2];
    const float* emb_W   = (const float*)d_in[3];
    const float* k0      = (const float*)d_in[4];
    const float* b0      = (const float*)d_in[5];
    const float* k1      = (const float*)d_in[6];
    const float* b1      = (const float*)d_in[7];
    const float* out_W   = (const float*)d_in[8];
    const float* out_b   = (const float*)d_in[9];
    float* out = (float*)d_out;

    char* p = (char*)d_ws;
    ushort_t* Zb   = (ushort_t*)p;  p += (size_t)NROWS * 1024 * 2;    // 33.55 MB
    ushort_t* Xp   = (ushort_t*)p;  p += (size_t)NROWS * 1024 * 2;    // 33.55 MB
    ushort_t* out1 = (ushort_t*)p;  p += (size_t)NROWS * 256 * 2;     // 8.39 MB
    uchar_t*  h2f8 = (uchar_t*)p;   p += (size_t)NROWS * 256;         // 4.19 MB
    uchar_t*  Wsw1 = (uchar_t*)p;   p += (size_t)1024 * 256;          // 256 KB
    uchar_t*  Wsw2 = (uchar_t*)p;   p += (size_t)1024 * 256;          // 256 KB
    ushort_t* W2x  = (ushort_t*)p;  p += (size_t)1024 * 256 * 2;      // 512 KB
    ushort_t* W1xT = (ushort_t*)p;  p += (size_t)1024 * 128 * 2;      // 256 KB
    uchar_t*  Wt8  = (uchar_t*)p;   p += (size_t)NT8 * 4096;          // 2.57 MB
    float*    obp  = (float*)p;     p += (size_t)VPAD * 4;
    unsigned* prog1  = (unsigned*)p; p += 16 * 4;
    unsigned* xflag  = (unsigned*)p; p += 64 * 4;
    unsigned* h2prog = (unsigned*)p; p += 64 * 4;

    hipMemsetAsync(d_out, 0, sizeof(float), stream);
    hipMemsetAsync(prog1, 0, 144 * 4, stream);

    wtx<<<dim3(16, 2), 256, 0, stream>>>(k0, W1xT);
    zgemm_mf<<<dim3(256, 4), 256, 0, stream>>>(W1xT, b0, emb_W, input_x, Zb);
    wf8k128<<<64, 256, 0, stream>>>(k0 + (size_t)EE * 1024, Wsw1);
    wf8k128<<<64, 256, 0, stream>>>(k1 + (size_t)HH * 1024, Wsw2);
    wtgen<<<dim3(16, 4), 256, 0, stream>>>(k1, W2x);
    wtf8<<<NT8, 256, 0, stream>>>(out_W, Wt8);
    obset_kernel<<<(VPAD + 255) / 256, 256, 0, stream>>>(out_b, obp);

    pipe_kernel<<<256, 512, 0, stream>>>(Wsw1, Wsw2, W2x, b1, lens, Zb, out1, Xp,
                                         h2f8, Wt8, obp, input_y, out,
                                         prog1, xflag, h2prog);
}

// Round 19
// 1248.277 us; speedup vs baseline: 1.3415x; 1.1053x over previous
//
#include <hip/hip_runtime.h>
#include <hip/hip_fp8.h>
#include <cmath>

#define SS 512
#define BB 32
#define EE 128
#define HH 256
#define VV 10000
#define NROWS (SS*BB)   // 16384
#define VPAD 10048
#define NT8 (VPAD/16)   // 628 fp8 B-tiles

typedef unsigned short ushort_t;
typedef unsigned char uchar_t;
typedef __attribute__((ext_vector_type(8))) short bf16x8;
typedef __attribute__((ext_vector_type(8))) int i32x8;
typedef __attribute__((ext_vector_type(4))) float f32x4;

#define MFMA(a,b,c)  __builtin_amdgcn_mfma_f32_16x16x32_bf16((a),(b),(c),0,0,0)
#define MFMAS(a,b,c) __builtin_amdgcn_mfma_scale_f32_16x16x128_f8f6f4((a),(b),(c),0,0,0,0x7F7F7F7F,0,0x7F7F7F7F)

__device__ __forceinline__ ushort_t f2bf(float x) {
    unsigned u = __float_as_uint(x);
    u = (u + 0x7FFFu + ((u >> 16) & 1u)) >> 16;   // RNE
    return (ushort_t)u;
}
__device__ __forceinline__ float bf2f(ushort_t h) {
    return __uint_as_float(((unsigned)h) << 16);
}
__device__ __forceinline__ uchar_t f2fp8(float x) {
    __hip_fp8_e4m3 t(x);                           // OCP e4m3
    return (uchar_t)t.__x;
}
__device__ __forceinline__ float sigf(float x) { return 1.0f / (1.0f + __expf(-x)); }
__device__ __forceinline__ float tanhf_(float x) { return 1.0f - 2.0f / (__expf(2.0f * x) + 1.0f); }

__device__ __forceinline__ i32x8 ldfrag(const uchar_t* base, int lane) {
    i32x8 r;
    ((uint4*)&r)[0] = *(const uint4*)(base + lane * 16);
    ((uint4*)&r)[1] = *(const uint4*)(base + 1024 + lane * 16);
    return r;
}

__device__ __forceinline__ void pollc(unsigned* p, unsigned target) {
    int it = 0;
    while (__hip_atomic_load(p, __ATOMIC_RELAXED, __HIP_MEMORY_SCOPE_AGENT) < target) {
        __builtin_amdgcn_s_sleep(4);
        if (++it > 50000000) break;    // anti-hang cap
    }
}
__device__ __forceinline__ void reladd(unsigned* p) {
    __hip_atomic_fetch_add(p, 1u, __ATOMIC_RELEASE, __HIP_MEMORY_SCOPE_AGENT);
}

// ---------------- k0 x-part transpose (R16-validated) ----------------
__global__ __launch_bounds__(256)
void wtx(const float* __restrict__ src, ushort_t* __restrict__ dst)
{
    __shared__ float tile[64][65];
    const int tid = threadIdx.x;
    const int n0 = blockIdx.x * 64, k0_ = blockIdx.y * 64;
    for (int i = tid; i < 4096; i += 256) {
        const int kk = i >> 6, nn = i & 63;
        tile[kk][nn] = src[(size_t)(k0_ + kk) * 1024 + n0 + nn];
    }
    __syncthreads();
    for (int i = tid; i < 4096; i += 256) {
        const int nn = i >> 6, kk = i & 63;
        dst[(size_t)(n0 + nn) * 128 + k0_ + kk] = f2bf(tile[kk][nn]);
    }
}

// ---------------- MFMA zgemm, gate-interleaved out (R17-validated) ----------------
__global__ __launch_bounds__(256)
void zgemm_mf(const ushort_t* __restrict__ W1xT, const float* __restrict__ b0v,
              const float* __restrict__ emb, const int* __restrict__ idx,
              ushort_t* __restrict__ Zb)
{
    __shared__ ushort_t ash[64 * 136];
    const int tid = threadIdx.x;
    const int w = tid >> 6, lane = tid & 63;
    const int q = lane >> 4, n16 = lane & 15;
    const int m0 = blockIdx.x * 64;
    const int nbase = blockIdx.y * 256;

    for (int i = tid; i < 64 * 32; i += 256) {
        const int r_ = i >> 5, c4 = i & 31;
        const int m = m0 + r_;
        const int t = m >> 5, b = m & 31;
        const int id = idx[b * SS + t];
        const float4 v = ((const float4*)emb)[(size_t)id * 32 + c4];
        ushort_t o4[4] = { f2bf(v.x), f2bf(v.y), f2bf(v.z), f2bf(v.w) };
        *(uint2*)&ash[r_ * 136 + c4 * 4] = *(uint2*)o4;
    }
    __syncthreads();

    bf16x8 A[4];
#pragma unroll
    for (int kb = 0; kb < 4; kb++)
        A[kb] = *(const bf16x8*)&ash[(w * 16 + n16) * 136 + kb * 32 + q * 8];

#pragma unroll 1
    for (int nt = 0; nt < 16; nt++) {
        const int n = nbase + nt * 16 + n16;
        bf16x8 B[4];
#pragma unroll
        for (int kb = 0; kb < 4; kb++)
            B[kb] = *(const bf16x8*)&W1xT[(size_t)n * 128 + kb * 32 + q * 8];
        f32x4 C = (f32x4){0.f, 0.f, 0.f, 0.f};
#pragma unroll
        for (int kb = 0; kb < 4; kb++)
            C = MFMA(A[kb], B[kb], C);
        const float bv = b0v[n];
        const int g = n >> 8, u = n & 255;
#pragma unroll
        for (int r = 0; r < 4; r++)
            Zb[(size_t)(m0 + w * 16 + q * 4 + r) * 1024 + u * 4 + g] = f2bf(C[r] + bv);
    }
}

// ---------------- h-part weights -> fp8 K=128 frag layout (R12-validated) ----------
__global__ __launch_bounds__(256)
void wf8k128(const float* __restrict__ src, uchar_t* __restrict__ dst)
{
    const int nt = blockIdx.x;
    const int t = threadIdx.x;
    const int kk = t >> 7, h = (t >> 6) & 1, l = t & 63;
    const int q = l >> 4, n16 = l & 15;
    const int col = (nt >> 4) * 256 + (nt & 15) * 16 + n16;
    uchar_t v[16];
#pragma unroll
    for (int j = 0; j < 16; j++) {
        const int k = kk * 128 + q * 32 + h * 16 + j;
        v[j] = f2fp8(src[(size_t)k * 1024 + col]);
    }
    *(uint4*)&dst[(((size_t)(nt * 2 + kk) * 2 + h) * 64 + l) * 16] = *(uint4*)v;
}

// ---------------- out_W -> fp8 K=128 frag layout (R14-validated) ----------
__global__ __launch_bounds__(256)
void wtf8(const float* __restrict__ W, uchar_t* __restrict__ dst)
{
    const int nt = blockIdx.x;
    const int t = threadIdx.x;
    const int kk = t >> 7, h = (t >> 6) & 1, l = t & 63;
    const int q = l >> 4, n16 = l & 15;
    const int col = nt * 16 + n16;
    uchar_t v[16];
#pragma unroll
    for (int j = 0; j < 16; j++) {
        const int k = kk * 128 + q * 32 + h * 16 + j;
        v[j] = (col < VV) ? f2fp8(W[(size_t)k * VV + col]) : (uchar_t)0;
    }
    *(uint4*)&dst[(((size_t)(nt * 2 + kk) * 2 + h) * 64 + l) * 16] = *(uint4*)v;
}

// ---------------- fp32[256 x 1024] -> bf16 [1024][256] transpose (R6-validated) ------
__global__ __launch_bounds__(256)
void wtgen(const float* __restrict__ src, ushort_t* __restrict__ dst)
{
    __shared__ float tile[64][65];
    const int tid = threadIdx.x;
    const int n0 = blockIdx.x * 64, k0 = blockIdx.y * 64;
    for (int i = tid; i < 4096; i += 256) {
        const int kk = i >> 6, nn = i & 63;
        tile[kk][nn] = src[(size_t)(k0 + kk) * 1024 + n0 + nn];
    }
    __syncthreads();
    for (int i = tid; i < 4096; i += 256) {
        const int nn = i >> 6, kk = i & 63;
        dst[(size_t)(n0 + nn) * 256 + k0 + kk] = f2bf(tile[kk][nn]);
    }
}

__global__ __launch_bounds__(256)
void obset_kernel(const float* __restrict__ ob, float* __restrict__ obp)
{
    const int v = blockIdx.x * 256 + threadIdx.x;
    if (v < VPAD) obp[v] = (v < VV) ? ob[v] : -INFINITY;
}

// ---------------- LSTM recurrence role (R18 + St VGPR-resident, 16-step fences) -------
__device__ __forceinline__ void lstm_role(
    uchar_t* Bl, uchar_t* h8buf,
    const uchar_t* __restrict__ Wsw, const ushort_t* __restrict__ zin,
    const int* __restrict__ lens, ushort_t* __restrict__ outp,
    uchar_t* __restrict__ hf8,
    unsigned* prog1, unsigned* xflag, unsigned* h2prog,
    int b, bool isL1)
{
    uchar_t (*h8)[256] = (uchar_t (*)[256])h8buf;
    const int tid = threadIdx.x;
    const int w = tid >> 6, lane = tid & 63;
    const int q = lane >> 4, n16 = lane & 15;
    const int len = lens[b];
    const int jown = q >> 1;
    const int unit = w * 32 + jown * 16 + n16;

#pragma unroll
    for (int li = 0; li < 3; li++) {
        const int nt = li * 16 + w * 2 + 1;
#pragma unroll
        for (int fh = 0; fh < 4; fh++) {
            const size_t s = (((size_t)nt * 4 + fh) * 64 + lane) * 16;
            const size_t d = (((size_t)(w * 3 + li) * 4 + fh) * 64 + lane) * 16;
            *(uint4*)&Bl[d] = *(const uint4*)&Wsw[s];
        }
    }
    i32x8 Bv[4][2];
#pragma unroll
    for (int g = 0; g < 4; g++) {
        const int nt = g * 16 + w * 2;
#pragma unroll
        for (int kk = 0; kk < 2; kk++)
            Bv[g][kk] = ldfrag(&Wsw[(size_t)nt * 4096 + kk * 2048], lane);
    }
    i32x8 Sv[2];                       // tile (3,1) — loop-invariant, VGPR-resident
    {
        const int nt = 3 * 16 + w * 2 + 1;
#pragma unroll
        for (int kk = 0; kk < 2; kk++)
            Sv[kk] = ldfrag(&Wsw[(size_t)nt * 4096 + kk * 2048], lane);
    }
    if (tid < 256) { h8[0][tid] = 0; h8[1][tid] = 0; }
    float c = 0.f;
    __syncthreads();

    const uchar_t* Lb0 = &Bl[(size_t)(w * 3) * 4096];

    for (int t = 0; t < SS; t++) {
        if (t >= len) {                // uniform early exit: zero rest, release rest
            uint4 zz; zz.x = zz.y = zz.z = zz.w = 0u;
            if (outp) {
                const int nseg = (SS - t) * 32;
                for (int i = tid; i < nseg; i += 512) {
                    const int tt = t + (i >> 5), seg = i & 31;
                    *(uint4*)&outp[((size_t)tt * 32 + b) * 256 + seg * 8] = zz;
                }
            }
            if (hf8) {
                const int nseg8 = (SS - t) * 16;
                for (int i = tid; i < nseg8; i += 512) {
                    const int tt = t + (i >> 4), seg = i & 15;
                    *(uint4*)&hf8[((size_t)tt * 32 + b) * 256 + seg * 16] = zz;
                }
            }
            __syncthreads();           // drain zero-fill stores
            if (tid == 0) {
                if (isL1) for (int cc = t >> 5; cc < 16; cc++) reladd(&prog1[cc]);
                else      for (int cc = t >> 3; cc < 64; cc++) reladd(&h2prog[cc]);
            }
            break;
        }
        if (!isL1 && (t & 15) == 0) {  // consume 2 xgemm chunks per fence
            if (tid == 0) {
                pollc(&xflag[t >> 3], 1u);
                pollc(&xflag[(t >> 3) + 1], 1u);
            }
            __syncthreads();
            __builtin_amdgcn_fence(__ATOMIC_ACQUIRE, "agent");
        }
        const size_t row = (size_t)t * 32 + b;
        ushort_t z4[4];
        *(uint2*)z4 = *(const uint2*)&zin[row * 1024 + unit * 4];

        const int rd = t & 1, wr = rd ^ 1;
        i32x8 Af0, Af1;
        ((uint4*)&Af0)[0] = *(const uint4*)&h8[rd][q * 32];
        ((uint4*)&Af0)[1] = *(const uint4*)&h8[rd][q * 32 + 16];
        ((uint4*)&Af1)[0] = *(const uint4*)&h8[rd][128 + q * 32];
        ((uint4*)&Af1)[1] = *(const uint4*)&h8[rd][128 + q * 32 + 16];

        float gvv[4];
#pragma unroll
        for (int g = 0; g < 4; g++) {
            f32x4 C0 = (f32x4){0.f,0.f,0.f,0.f}, C1 = (f32x4){0.f,0.f,0.f,0.f};
            C0 = MFMAS(Af0, Bv[g][0], C0);
            C0 = MFMAS(Af1, Bv[g][1], C0);
            if (g < 3) {
                const uchar_t* p = Lb0 + (size_t)g * 4096;
                C1 = MFMAS(Af0, ldfrag(p, lane), C1);
                C1 = MFMAS(Af1, ldfrag(p + 2048, lane), C1);
            } else {
                C1 = MFMAS(Af0, Sv[0], C1);
                C1 = MFMAS(Af1, Sv[1], C1);
            }
            gvv[g] = jown ? C1[0] : C0[0];
        }
        {
            const float zi = bf2f(z4[0]) + gvv[0];
            const float zg = bf2f(z4[1]) + gvv[1];
            const float zf = bf2f(z4[2]) + gvv[2];
            const float zo = bf2f(z4[3]) + gvv[3];
            const float cn = sigf(zf + 1.0f) * c + sigf(zi) * tanhf_(zg);
            const float hn = sigf(zo) * tanhf_(cn);
            c = cn;
            const uchar_t h8v = f2fp8(hn);
            h8[wr][unit] = h8v;
            if (outp) outp[row * 256 + unit] = f2bf(hn);
            if (hf8) hf8[row * 256 + unit] = h8v;
        }
        __syncthreads();               // h8[wr] ready + all stores drained
        if (tid == 0) {
            if (isL1) { if (((t + 1) & 31) == 0) reladd(&prog1[t >> 5]); }
            else      { if (((t + 1) & 7)  == 0) reladd(&h2prog[t >> 3]); }
        }
    }
}

// ---------------- fused pipeline kernel: 256 co-resident blocks (R18-validated) -------
// blk 0..31: lstm1 | 32..95: xgemm (8 t each) | 96..127: lstm2 | 128..255: ce.
__global__ __launch_bounds__(512, 1)
void pipe_kernel(const uchar_t* __restrict__ Wsw1, const uchar_t* __restrict__ Wsw2,
                 const ushort_t* __restrict__ W2x, const float* __restrict__ b1v,
                 const int* __restrict__ lens, const ushort_t* __restrict__ Zb,
                 ushort_t* __restrict__ out1, ushort_t* __restrict__ Xp,
                 uchar_t* __restrict__ hf8, const uchar_t* __restrict__ Wt8,
                 const float* __restrict__ obp, const int* __restrict__ y,
                 float* __restrict__ out,
                 unsigned* __restrict__ prog1, unsigned* __restrict__ xflag,
                 unsigned* __restrict__ h2prog)
{
    __shared__ uchar_t smem[98816];
    const int tid = threadIdx.x;
    const int blk = blockIdx.x;
    const int w = tid >> 6, lane = tid & 63;
    const int q = lane >> 4, n16 = lane & 15;

    if (blk < 32) {
        lstm_role(smem, smem + 98304, Wsw1, Zb, lens, out1, nullptr,
                  prog1, xflag, h2prog, blk, true);
    } else if (blk < 96) {
        // ---------------- xgemm role: timesteps [b2*8, b2*8+8) ----------------
        ushort_t* ash = (ushort_t*)smem;           // 128 x 264
        const int b2 = blk - 32;
        if (tid == 0) pollc(&prog1[b2 >> 2], 32u);
        __syncthreads();
        __builtin_amdgcn_fence(__ATOMIC_ACQUIRE, "agent");
#pragma unroll 1
        for (int half = 0; half < 2; half++) {
            const int m0 = b2 * 256 + half * 128;
            if (half) __syncthreads();             // protect ash overwrite
            for (int i = tid; i < 128 * 32; i += 512) {
                const int r_ = i >> 5, s_ = i & 31;
                *(uint4*)&ash[r_ * 264 + s_ * 8] =
                    *(const uint4*)&out1[(size_t)(m0 + r_) * 256 + s_ * 8];
            }
            __syncthreads();
#pragma unroll 1
            for (int i = 0; i < 8; i++) {
                const int n = (w * 8 + i) * 16 + n16;
                bf16x8 Bfr[8];
#pragma unroll
                for (int kb = 0; kb < 8; kb++)
                    Bfr[kb] = *(const bf16x8*)&W2x[(size_t)n * 256 + kb * 32 + q * 8];
                const float bval = b1v[n];
                const int g = n >> 8, u = n & 255;
                f32x4 Cc[8];
#pragma unroll
                for (int mt = 0; mt < 8; mt++) {
                    Cc[mt] = (f32x4){0.f, 0.f, 0.f, 0.f};
                    bf16x8 Af[8];
#pragma unroll
                    for (int kb = 0; kb < 8; kb++)
                        Af[kb] = *(const bf16x8*)&ash[(mt * 16 + n16) * 264 + kb * 32 + q * 8];
#pragma unroll
                    for (int kb = 0; kb < 8; kb++)
                        Cc[mt] = MFMA(Af[kb], Bfr[kb], Cc[mt]);
                }
#pragma unroll
                for (int mt = 0; mt < 8; mt++)
#pragma unroll
                    for (int r = 0; r < 4; r++) {
                        const int rrow = m0 + mt * 16 + q * 4 + r;
                        Xp[(size_t)rrow * 1024 + u * 4 + g] = f2bf(Cc[mt][r] + bval);
                    }
            }
        }
        __syncthreads();               // drain Xp stores
        if (tid == 0)
            __hip_atomic_store(&xflag[b2], 1u, __ATOMIC_RELEASE, __HIP_MEMORY_SCOPE_AGENT);
    } else if (blk < 128) {
        lstm_role(smem, smem + 98304, Wsw2, Xp, lens, nullptr, hf8,
                  prog1, xflag, h2prog, blk - 96, false);
    } else {
        // ---------------- ce role: rows [cb*128, +128) ----------------
        float* lsw = (float*)smem;                 // [4][64]
        float* tgt64 = (float*)(smem + 1024);      // [64]
        const int cb = blk - 128;
        if (tid == 0) pollc(&h2prog[cb >> 1], 32u);
        __syncthreads();
        __builtin_amdgcn_fence(__ATOMIC_ACQUIRE, "agent");
#pragma unroll 1
        for (int half = 0; half < 2; half++) {
            const int m0 = cb * 128 + half * 64;
            __syncthreads();           // protect tgt64/lsw reuse
            if (tid < 64) tgt64[tid] = 0.f;
            i32x8 A8[4][2];
            int yv[16];
            float lsum[16];
            if (tid < 256) {
#pragma unroll
                for (int mt = 0; mt < 4; mt++) {
                    const size_t rbase = (size_t)(m0 + mt * 16 + n16) * 256;
#pragma unroll
                    for (int kk = 0; kk < 2; kk++) {
                        ((uint4*)&A8[mt][kk])[0] = *(const uint4*)&hf8[rbase + kk * 128 + q * 32];
                        ((uint4*)&A8[mt][kk])[1] = *(const uint4*)&hf8[rbase + kk * 128 + q * 32 + 16];
                    }
                }
#pragma unroll
                for (int mt = 0; mt < 4; mt++)
#pragma unroll
                    for (int r = 0; r < 4; r++) {
                        const int m = m0 + mt * 16 + q * 4 + r;
                        yv[mt * 4 + r] = y[(m & 31) * SS + (m >> 5)];
                    }
#pragma unroll
                for (int i = 0; i < 16; i++) lsum[i] = 0.f;
            }
            __syncthreads();           // tgt64 init visible
            if (tid < 256) {
                for (int tile = 0; tile < 157; tile++) {
                    const int nt = w * 157 + tile;
                    const int n = nt * 16 + n16;
                    const i32x8 B0 = ldfrag(&Wt8[(size_t)(nt * 2 + 0) * 2048], lane);
                    const i32x8 B1 = ldfrag(&Wt8[(size_t)(nt * 2 + 1) * 2048], lane);
                    const float obv = obp[n];
                    f32x4 C[4];
#pragma unroll
                    for (int mt = 0; mt < 4; mt++) {
                        C[mt] = (f32x4){0.f, 0.f, 0.f, 0.f};
                        C[mt] = MFMAS(A8[mt][0], B0, C[mt]);
                        C[mt] = MFMAS(A8[mt][1], B1, C[mt]);
                    }
#pragma unroll
                    for (int mt = 0; mt < 4; mt++)
#pragma unroll
                        for (int r = 0; r < 4; r++) {
                            const float sc = C[mt][r] + obv;
                            if (n == yv[mt * 4 + r]) tgt64[mt * 16 + q * 4 + r] = sc;
                            lsum[mt * 4 + r] += __expf(sc - 16.0f);
                        }
                }
#pragma unroll
                for (int i = 0; i < 16; i++) {
                    float v = lsum[i];
                    v += __shfl_xor(v, 1, 16); v += __shfl_xor(v, 2, 16);
                    v += __shfl_xor(v, 4, 16); v += __shfl_xor(v, 8, 16);
                    lsum[i] = v;
                }
                if (n16 == 0)
#pragma unroll
                    for (int i = 0; i < 16; i++)
                        lsw[w * 64 + (i >> 2) * 16 + q * 4 + (i & 3)] = lsum[i];
            }
            __syncthreads();
            if (tid < 64) {
                const float l = lsw[tid] + lsw[64 + tid] + lsw[128 + tid] + lsw[192 + tid];
                const float lse = 16.0f + __logf(l);
                const int m = m0 + tid;
                const int tt = m >> 5, bb = m & 31;
                const int yvv = y[bb * SS + tt];
                float local = (yvv != 0) ? (lse - tgt64[tid]) / (32.0f * (float)lens[bb]) : 0.f;
                for (int off = 1; off < 64; off <<= 1) local += __shfl_xor(local, off, 64);
                if (tid == 0) atomicAdd(out, local);
            }
        }
    }
}

extern "C" void kernel_launch(void* const* d_in, const int* in_sizes, int n_in,
                              void* d_out, int out_size, void* d_ws, size_t ws_size,
                              hipStream_t stream)
{
    const int*   input_x = (const int*)  d_in[0];
    const int*   input_y = (const int*)  d_in[1];
    const int*   lens    = (const int*)  d_in[2];
    const float* emb_W   = (const float*)d_in[3];
    const float* k0      = (const float*)d_in[4];
    const float* b0      = (const float*)d_in[5];
    const float* k1      = (const float*)d_in[6];
    const float* b1      = (const float*)d_in[7];
    const float* out_W   = (const float*)d_in[8];
    const float* out_b   = (const float*)d_in[9];
    float* out = (float*)d_out;

    char* p = (char*)d_ws;
    ushort_t* Zb   = (ushort_t*)p;  p += (size_t)NROWS * 1024 * 2;    // 33.55 MB
    ushort_t* Xp   = (ushort_t*)p;  p += (size_t)NROWS * 1024 * 2;    // 33.55 MB
    ushort_t* out1 = (ushort_t*)p;  p += (size_t)NROWS * 256 * 2;     // 8.39 MB
    uchar_t*  h2f8 = (uchar_t*)p;   p += (size_t)NROWS * 256;         // 4.19 MB
    uchar_t*  Wsw1 = (uchar_t*)p;   p += (size_t)1024 * 256;          // 256 KB
    uchar_t*  Wsw2 = (uchar_t*)p;   p += (size_t)1024 * 256;          // 256 KB
    ushort_t* W2x  = (ushort_t*)p;  p += (size_t)1024 * 256 * 2;      // 512 KB
    ushort_t* W1xT = (ushort_t*)p;  p += (size_t)1024 * 128 * 2;      // 256 KB
    uchar_t*  Wt8  = (uchar_t*)p;   p += (size_t)NT8 * 4096;          // 2.57 MB
    float*    obp  = (float*)p;     p += (size_t)VPAD * 4;
    unsigned* prog1  = (unsigned*)p; p += 16 * 4;
    unsigned* xflag  = (unsigned*)p; p += 64 * 4;
    unsigned* h2prog = (unsigned*)p; p += 64 * 4;

    hipMemsetAsync(d_out, 0, sizeof(float), stream);
    hipMemsetAsync(prog1, 0, 144 * 4, stream);

    wtx<<<dim3(16, 2), 256, 0, stream>>>(k0, W1xT);
    zgemm_mf<<<dim3(256, 4), 256, 0, stream>>>(W1xT, b0, emb_W, input_x, Zb);
    wf8k128<<<64, 256, 0, stream>>>(k0 + (size_t)EE * 1024, Wsw1);
    wf8k128<<<64, 256, 0, stream>>>(k1 + (size_t)HH * 1024, Wsw2);
    wtgen<<<dim3(16, 4), 256, 0, stream>>>(k1, W2x);
    wtf8<<<NT8, 256, 0, stream>>>(out_W, Wt8);
    obset_kernel<<<(VPAD + 255) / 256, 256, 0, stream>>>(out_b, obp);

    pipe_kernel<<<256, 512, 0, stream>>>(Wsw1, Wsw2, W2x, b1, lens, Zb, out1, Xp,
                                         h2f8, Wt8, obp, input_y, out,
                                         prog1, xflag, h2prog);
}

// Round 20
// 1193.178 us; speedup vs baseline: 1.4034x; 1.0462x over previous
//
#include <hip/hip_runtime.h>
#include <hip/hip_fp8.h>
#include <cmath>

#define SS 512
#define BB 32
#define EE 128
#define HH 256
#define VV 10000
#define NROWS (SS*BB)   // 16384
#define VPAD 10048
#define NT8 (VPAD/16)   // 628 fp8 B-tiles

typedef unsigned short ushort_t;
typedef unsigned char uchar_t;
typedef __attribute__((ext_vector_type(8))) short bf16x8;
typedef __attribute__((ext_vector_type(8))) int i32x8;
typedef __attribute__((ext_vector_type(4))) float f32x4;

#define MFMA(a,b,c)  __builtin_amdgcn_mfma_f32_16x16x32_bf16((a),(b),(c),0,0,0)
#define MFMAS(a,b,c) __builtin_amdgcn_mfma_scale_f32_16x16x128_f8f6f4((a),(b),(c),0,0,0,0x7F7F7F7F,0,0x7F7F7F7F)

__device__ __forceinline__ ushort_t f2bf(float x) {
    unsigned u = __float_as_uint(x);
    u = (u + 0x7FFFu + ((u >> 16) & 1u)) >> 16;   // RNE
    return (ushort_t)u;
}
__device__ __forceinline__ float bf2f(ushort_t h) {
    return __uint_as_float(((unsigned)h) << 16);
}
__device__ __forceinline__ uchar_t f2fp8(float x) {
    __hip_fp8_e4m3 t(x);                           // OCP e4m3
    return (uchar_t)t.__x;
}
__device__ __forceinline__ float sigf(float x) { return 1.0f / (1.0f + __expf(-x)); }
__device__ __forceinline__ float tanhf_(float x) { return 1.0f - 2.0f / (__expf(2.0f * x) + 1.0f); }

__device__ __forceinline__ i32x8 ldfrag(const uchar_t* base, int lane) {
    i32x8 r;
    ((uint4*)&r)[0] = *(const uint4*)(base + lane * 16);
    ((uint4*)&r)[1] = *(const uint4*)(base + 1024 + lane * 16);
    return r;
}

__device__ __forceinline__ void pollc(unsigned* p, unsigned target) {
    int it = 0;
    while (__hip_atomic_load(p, __ATOMIC_RELAXED, __HIP_MEMORY_SCOPE_AGENT) < target) {
        __builtin_amdgcn_s_sleep(4);
        if (++it > 50000000) break;    // anti-hang cap
    }
}
__device__ __forceinline__ void reladd(unsigned* p) {
    __hip_atomic_fetch_add(p, 1u, __ATOMIC_RELEASE, __HIP_MEMORY_SCOPE_AGENT);
}

// ---------------- k0 x-part transpose (R16-validated) ----------------
__global__ __launch_bounds__(256)
void wtx(const float* __restrict__ src, ushort_t* __restrict__ dst)
{
    __shared__ float tile[64][65];
    const int tid = threadIdx.x;
    const int n0 = blockIdx.x * 64, k0_ = blockIdx.y * 64;
    for (int i = tid; i < 4096; i += 256) {
        const int kk = i >> 6, nn = i & 63;
        tile[kk][nn] = src[(size_t)(k0_ + kk) * 1024 + n0 + nn];
    }
    __syncthreads();
    for (int i = tid; i < 4096; i += 256) {
        const int nn = i >> 6, kk = i & 63;
        dst[(size_t)(n0 + nn) * 128 + k0_ + kk] = f2bf(tile[kk][nn]);
    }
}

// ---------------- MFMA zgemm, gate-interleaved out (R17-validated) ----------------
__global__ __launch_bounds__(256)
void zgemm_mf(const ushort_t* __restrict__ W1xT, const float* __restrict__ b0v,
              const float* __restrict__ emb, const int* __restrict__ idx,
              ushort_t* __restrict__ Zb)
{
    __shared__ ushort_t ash[64 * 136];
    const int tid = threadIdx.x;
    const int w = tid >> 6, lane = tid & 63;
    const int q = lane >> 4, n16 = lane & 15;
    const int m0 = blockIdx.x * 64;
    const int nbase = blockIdx.y * 256;

    for (int i = tid; i < 64 * 32; i += 256) {
        const int r_ = i >> 5, c4 = i & 31;
        const int m = m0 + r_;
        const int t = m >> 5, b = m & 31;
        const int id = idx[b * SS + t];
        const float4 v = ((const float4*)emb)[(size_t)id * 32 + c4];
        ushort_t o4[4] = { f2bf(v.x), f2bf(v.y), f2bf(v.z), f2bf(v.w) };
        *(uint2*)&ash[r_ * 136 + c4 * 4] = *(uint2*)o4;
    }
    __syncthreads();

    bf16x8 A[4];
#pragma unroll
    for (int kb = 0; kb < 4; kb++)
        A[kb] = *(const bf16x8*)&ash[(w * 16 + n16) * 136 + kb * 32 + q * 8];

#pragma unroll 1
    for (int nt = 0; nt < 16; nt++) {
        const int n = nbase + nt * 16 + n16;
        bf16x8 B[4];
#pragma unroll
        for (int kb = 0; kb < 4; kb++)
            B[kb] = *(const bf16x8*)&W1xT[(size_t)n * 128 + kb * 32 + q * 8];
        f32x4 C = (f32x4){0.f, 0.f, 0.f, 0.f};
#pragma unroll
        for (int kb = 0; kb < 4; kb++)
            C = MFMA(A[kb], B[kb], C);
        const float bv = b0v[n];
        const int g = n >> 8, u = n & 255;
#pragma unroll
        for (int r = 0; r < 4; r++)
            Zb[(size_t)(m0 + w * 16 + q * 4 + r) * 1024 + u * 4 + g] = f2bf(C[r] + bv);
    }
}

// ---------------- h-part weights -> fp8 K=128 frag layout (R12-validated) ----------
__global__ __launch_bounds__(256)
void wf8k128(const float* __restrict__ src, uchar_t* __restrict__ dst)
{
    const int nt = blockIdx.x;
    const int t = threadIdx.x;
    const int kk = t >> 7, h = (t >> 6) & 1, l = t & 63;
    const int q = l >> 4, n16 = l & 15;
    const int col = (nt >> 4) * 256 + (nt & 15) * 16 + n16;
    uchar_t v[16];
#pragma unroll
    for (int j = 0; j < 16; j++) {
        const int k = kk * 128 + q * 32 + h * 16 + j;
        v[j] = f2fp8(src[(size_t)k * 1024 + col]);
    }
    *(uint4*)&dst[(((size_t)(nt * 2 + kk) * 2 + h) * 64 + l) * 16] = *(uint4*)v;
}

// ---------------- out_W -> fp8 K=128 frag layout (R14-validated) ----------
__global__ __launch_bounds__(256)
void wtf8(const float* __restrict__ W, uchar_t* __restrict__ dst)
{
    const int nt = blockIdx.x;
    const int t = threadIdx.x;
    const int kk = t >> 7, h = (t >> 6) & 1, l = t & 63;
    const int q = l >> 4, n16 = l & 15;
    const int col = nt * 16 + n16;
    uchar_t v[16];
#pragma unroll
    for (int j = 0; j < 16; j++) {
        const int k = kk * 128 + q * 32 + h * 16 + j;
        v[j] = (col < VV) ? f2fp8(W[(size_t)k * VV + col]) : (uchar_t)0;
    }
    *(uint4*)&dst[(((size_t)(nt * 2 + kk) * 2 + h) * 64 + l) * 16] = *(uint4*)v;
}

// ---------------- fp32[256 x 1024] -> bf16 [1024][256] transpose (R6-validated) ------
__global__ __launch_bounds__(256)
void wtgen(const float* __restrict__ src, ushort_t* __restrict__ dst)
{
    __shared__ float tile[64][65];
    const int tid = threadIdx.x;
    const int n0 = blockIdx.x * 64, k0 = blockIdx.y * 64;
    for (int i = tid; i < 4096; i += 256) {
        const int kk = i >> 6, nn = i & 63;
        tile[kk][nn] = src[(size_t)(k0 + kk) * 1024 + n0 + nn];
    }
    __syncthreads();
    for (int i = tid; i < 4096; i += 256) {
        const int nn = i >> 6, kk = i & 63;
        dst[(size_t)(n0 + nn) * 256 + k0 + kk] = f2bf(tile[kk][nn]);
    }
}

__global__ __launch_bounds__(256)
void obset_kernel(const float* __restrict__ ob, float* __restrict__ obp)
{
    const int v = blockIdx.x * 256 + threadIdx.x;
    if (v < VPAD) obp[v] = (v < VV) ? ob[v] : -INFINITY;
}

// ---------------- LSTM recurrence role (R19 + z software prefetch) ----------------
__device__ __forceinline__ void lstm_role(
    uchar_t* Bl, uchar_t* h8buf,
    const uchar_t* __restrict__ Wsw, const ushort_t* __restrict__ zin,
    const int* __restrict__ lens, ushort_t* __restrict__ outp,
    uchar_t* __restrict__ hf8,
    unsigned* prog1, unsigned* xflag, unsigned* h2prog,
    int b, bool isL1)
{
    uchar_t (*h8)[256] = (uchar_t (*)[256])h8buf;
    const int tid = threadIdx.x;
    const int w = tid >> 6, lane = tid & 63;
    const int q = lane >> 4, n16 = lane & 15;
    const int len = lens[b];
    const int jown = q >> 1;
    const int unit = w * 32 + jown * 16 + n16;

#pragma unroll
    for (int li = 0; li < 3; li++) {
        const int nt = li * 16 + w * 2 + 1;
#pragma unroll
        for (int fh = 0; fh < 4; fh++) {
            const size_t s = (((size_t)nt * 4 + fh) * 64 + lane) * 16;
            const size_t d = (((size_t)(w * 3 + li) * 4 + fh) * 64 + lane) * 16;
            *(uint4*)&Bl[d] = *(const uint4*)&Wsw[s];
        }
    }
    i32x8 Bv[4][2];
#pragma unroll
    for (int g = 0; g < 4; g++) {
        const int nt = g * 16 + w * 2;
#pragma unroll
        for (int kk = 0; kk < 2; kk++)
            Bv[g][kk] = ldfrag(&Wsw[(size_t)nt * 4096 + kk * 2048], lane);
    }
    i32x8 Sv[2];                       // tile (3,1) — loop-invariant, VGPR-resident
    {
        const int nt = 3 * 16 + w * 2 + 1;
#pragma unroll
        for (int kk = 0; kk < 2; kk++)
            Sv[kk] = ldfrag(&Wsw[(size_t)nt * 4096 + kk * 2048], lane);
    }
    if (tid < 256) { h8[0][tid] = 0; h8[1][tid] = 0; }
    float c = 0.f;
    __syncthreads();

    const uchar_t* Lb0 = &Bl[(size_t)(w * 3) * 4096];

    uint2 zreg;                        // z prefetch register
    bool zvalid = false;
    if (isL1) {                        // Zb fully materialized: prefetch t=0 now
        zreg = *(const uint2*)&zin[(size_t)(0 * 32 + b) * 1024 + unit * 4];
        zvalid = true;
    }

    for (int t = 0; t < SS; t++) {
        if (t >= len) {                // uniform early exit: zero rest, release rest
            uint4 zz; zz.x = zz.y = zz.z = zz.w = 0u;
            if (outp) {
                const int nseg = (SS - t) * 32;
                for (int i = tid; i < nseg; i += 512) {
                    const int tt = t + (i >> 5), seg = i & 31;
                    *(uint4*)&outp[((size_t)tt * 32 + b) * 256 + seg * 8] = zz;
                }
            }
            if (hf8) {
                const int nseg8 = (SS - t) * 16;
                for (int i = tid; i < nseg8; i += 512) {
                    const int tt = t + (i >> 4), seg = i & 15;
                    *(uint4*)&hf8[((size_t)tt * 32 + b) * 256 + seg * 16] = zz;
                }
            }
            __syncthreads();           // drain zero-fill stores
            if (tid == 0) {
                if (isL1) for (int cc = t >> 5; cc < 16; cc++) reladd(&prog1[cc]);
                else      for (int cc = t >> 3; cc < 64; cc++) reladd(&h2prog[cc]);
            }
            break;
        }
        if (!isL1 && (t & 15) == 0) {  // consume 2 xgemm chunks per fence
            if (tid == 0) {
                pollc(&xflag[t >> 3], 1u);
                pollc(&xflag[(t >> 3) + 1], 1u);
            }
            __syncthreads();
            __builtin_amdgcn_fence(__ATOMIC_ACQUIRE, "agent");
        }
        const size_t row = (size_t)t * 32 + b;
        ushort_t z4[4];
        if (zvalid) *(uint2*)z4 = zreg;                       // prefetched last step
        else        *(uint2*)z4 = *(const uint2*)&zin[row * 1024 + unit * 4];
        // prefetch z for t+1 (issued ~3000cy early; hides L3/HBM latency).
        // lstm2: only within the acquired window ((t+1)&15 != 0).
        if (t + 1 < SS && (isL1 || ((t + 1) & 15) != 0)) {
            zreg = *(const uint2*)&zin[(row + 32) * 1024 + unit * 4];
            zvalid = true;
        } else zvalid = false;

        const int rd = t & 1, wr = rd ^ 1;
        i32x8 Af0, Af1;
        ((uint4*)&Af0)[0] = *(const uint4*)&h8[rd][q * 32];
        ((uint4*)&Af0)[1] = *(const uint4*)&h8[rd][q * 32 + 16];
        ((uint4*)&Af1)[0] = *(const uint4*)&h8[rd][128 + q * 32];
        ((uint4*)&Af1)[1] = *(const uint4*)&h8[rd][128 + q * 32 + 16];

        float gvv[4];
#pragma unroll
        for (int g = 0; g < 4; g++) {
            f32x4 C0 = (f32x4){0.f,0.f,0.f,0.f}, C1 = (f32x4){0.f,0.f,0.f,0.f};
            C0 = MFMAS(Af0, Bv[g][0], C0);
            C0 = MFMAS(Af1, Bv[g][1], C0);
            if (g < 3) {
                const uchar_t* p = Lb0 + (size_t)g * 4096;
                C1 = MFMAS(Af0, ldfrag(p, lane), C1);
                C1 = MFMAS(Af1, ldfrag(p + 2048, lane), C1);
            } else {
                C1 = MFMAS(Af0, Sv[0], C1);
                C1 = MFMAS(Af1, Sv[1], C1);
            }
            gvv[g] = jown ? C1[0] : C0[0];
        }
        {
            const float zi = bf2f(z4[0]) + gvv[0];
            const float zg = bf2f(z4[1]) + gvv[1];
            const float zf = bf2f(z4[2]) + gvv[2];
            const float zo = bf2f(z4[3]) + gvv[3];
            const float cn = sigf(zf + 1.0f) * c + sigf(zi) * tanhf_(zg);
            const float hn = sigf(zo) * tanhf_(cn);
            c = cn;
            const uchar_t h8v = f2fp8(hn);
            h8[wr][unit] = h8v;
            if (outp) outp[row * 256 + unit] = f2bf(hn);
            if (hf8) hf8[row * 256 + unit] = h8v;
        }
        __syncthreads();               // h8[wr] ready + all stores drained
        if (tid == 0) {
            if (isL1) { if (((t + 1) & 31) == 0) reladd(&prog1[t >> 5]); }
            else      { if (((t + 1) & 7)  == 0) reladd(&h2prog[t >> 3]); }
        }
    }
}

// ---------------- fused pipeline kernel: 256 co-resident blocks (R18/R19-validated) ---
// blk 0..31: lstm1 | 32..95: xgemm (8 t each) | 96..127: lstm2 | 128..255: ce.
__global__ __launch_bounds__(512, 1)
void pipe_kernel(const uchar_t* __restrict__ Wsw1, const uchar_t* __restrict__ Wsw2,
                 const ushort_t* __restrict__ W2x, const float* __restrict__ b1v,
                 const int* __restrict__ lens, const ushort_t* __restrict__ Zb,
                 ushort_t* __restrict__ out1, ushort_t* __restrict__ Xp,
                 uchar_t* __restrict__ hf8, const uchar_t* __restrict__ Wt8,
                 const float* __restrict__ obp, const int* __restrict__ y,
                 float* __restrict__ out,
                 unsigned* __restrict__ prog1, unsigned* __restrict__ xflag,
                 unsigned* __restrict__ h2prog)
{
    __shared__ uchar_t smem[98816];
    const int tid = threadIdx.x;
    const int blk = blockIdx.x;
    const int w = tid >> 6, lane = tid & 63;
    const int q = lane >> 4, n16 = lane & 15;

    if (blk < 32) {
        lstm_role(smem, smem + 98304, Wsw1, Zb, lens, out1, nullptr,
                  prog1, xflag, h2prog, blk, true);
    } else if (blk < 96) {
        // ---------------- xgemm role: timesteps [b2*8, b2*8+8) ----------------
        ushort_t* ash = (ushort_t*)smem;           // 128 x 264
        const int b2 = blk - 32;
        if (tid == 0) pollc(&prog1[b2 >> 2], 32u);
        __syncthreads();
        __builtin_amdgcn_fence(__ATOMIC_ACQUIRE, "agent");
#pragma unroll 1
        for (int half = 0; half < 2; half++) {
            const int m0 = b2 * 256 + half * 128;
            if (half) __syncthreads();             // protect ash overwrite
            for (int i = tid; i < 128 * 32; i += 512) {
                const int r_ = i >> 5, s_ = i & 31;
                *(uint4*)&ash[r_ * 264 + s_ * 8] =
                    *(const uint4*)&out1[(size_t)(m0 + r_) * 256 + s_ * 8];
            }
            __syncthreads();
#pragma unroll 1
            for (int i = 0; i < 8; i++) {
                const int n = (w * 8 + i) * 16 + n16;
                bf16x8 Bfr[8];
#pragma unroll
                for (int kb = 0; kb < 8; kb++)
                    Bfr[kb] = *(const bf16x8*)&W2x[(size_t)n * 256 + kb * 32 + q * 8];
                const float bval = b1v[n];
                const int g = n >> 8, u = n & 255;
                f32x4 Cc[8];
#pragma unroll
                for (int mt = 0; mt < 8; mt++) {
                    Cc[mt] = (f32x4){0.f, 0.f, 0.f, 0.f};
                    bf16x8 Af[8];
#pragma unroll
                    for (int kb = 0; kb < 8; kb++)
                        Af[kb] = *(const bf16x8*)&ash[(mt * 16 + n16) * 264 + kb * 32 + q * 8];
#pragma unroll
                    for (int kb = 0; kb < 8; kb++)
                        Cc[mt] = MFMA(Af[kb], Bfr[kb], Cc[mt]);
                }
#pragma unroll
                for (int mt = 0; mt < 8; mt++)
#pragma unroll
                    for (int r = 0; r < 4; r++) {
                        const int rrow = m0 + mt * 16 + q * 4 + r;
                        Xp[(size_t)rrow * 1024 + u * 4 + g] = f2bf(Cc[mt][r] + bval);
                    }
            }
        }
        __syncthreads();               // drain Xp stores
        if (tid == 0)
            __hip_atomic_store(&xflag[b2], 1u, __ATOMIC_RELEASE, __HIP_MEMORY_SCOPE_AGENT);
    } else if (blk < 128) {
        lstm_role(smem, smem + 98304, Wsw2, Xp, lens, nullptr, hf8,
                  prog1, xflag, h2prog, blk - 96, false);
    } else {
        // ---------------- ce role: rows [cb*128, +128) ----------------
        float* lsw = (float*)smem;                 // [4][64]
        float* tgt64 = (float*)(smem + 1024);      // [64]
        const int cb = blk - 128;
        if (tid == 0) pollc(&h2prog[cb >> 1], 32u);
        __syncthreads();
        __builtin_amdgcn_fence(__ATOMIC_ACQUIRE, "agent");
#pragma unroll 1
        for (int half = 0; half < 2; half++) {
            const int m0 = cb * 128 + half * 64;
            __syncthreads();           // protect tgt64/lsw reuse
            if (tid < 64) tgt64[tid] = 0.f;
            i32x8 A8[4][2];
            int yv[16];
            float lsum[16];
            if (tid < 256) {
#pragma unroll
                for (int mt = 0; mt < 4; mt++) {
                    const size_t rbase = (size_t)(m0 + mt * 16 + n16) * 256;
#pragma unroll
                    for (int kk = 0; kk < 2; kk++) {
                        ((uint4*)&A8[mt][kk])[0] = *(const uint4*)&hf8[rbase + kk * 128 + q * 32];
                        ((uint4*)&A8[mt][kk])[1] = *(const uint4*)&hf8[rbase + kk * 128 + q * 32 + 16];
                    }
                }
#pragma unroll
                for (int mt = 0; mt < 4; mt++)
#pragma unroll
                    for (int r = 0; r < 4; r++) {
                        const int m = m0 + mt * 16 + q * 4 + r;
                        yv[mt * 4 + r] = y[(m & 31) * SS + (m >> 5)];
                    }
#pragma unroll
                for (int i = 0; i < 16; i++) lsum[i] = 0.f;
            }
            __syncthreads();           // tgt64 init visible
            if (tid < 256) {
                for (int tile = 0; tile < 157; tile++) {
                    const int nt = w * 157 + tile;
                    const int n = nt * 16 + n16;
                    const i32x8 B0 = ldfrag(&Wt8[(size_t)(nt * 2 + 0) * 2048], lane);
                    const i32x8 B1 = ldfrag(&Wt8[(size_t)(nt * 2 + 1) * 2048], lane);
                    const float obv = obp[n];
                    f32x4 C[4];
#pragma unroll
                    for (int mt = 0; mt < 4; mt++) {
                        C[mt] = (f32x4){0.f, 0.f, 0.f, 0.f};
                        C[mt] = MFMAS(A8[mt][0], B0, C[mt]);
                        C[mt] = MFMAS(A8[mt][1], B1, C[mt]);
                    }
#pragma unroll
                    for (int mt = 0; mt < 4; mt++)
#pragma unroll
                        for (int r = 0; r < 4; r++) {
                            const float sc = C[mt][r] + obv;
                            if (n == yv[mt * 4 + r]) tgt64[mt * 16 + q * 4 + r] = sc;
                            lsum[mt * 4 + r] += __expf(sc - 16.0f);
                        }
                }
#pragma unroll
                for (int i = 0; i < 16; i++) {
                    float v = lsum[i];
                    v += __shfl_xor(v, 1, 16); v += __shfl_xor(v, 2, 16);
                    v += __shfl_xor(v, 4, 16); v += __shfl_xor(v, 8, 16);
                    lsum[i] = v;
                }
                if (n16 == 0)
#pragma unroll
                    for (int i = 0; i < 16; i++)
                        lsw[w * 64 + (i >> 2) * 16 + q * 4 + (i & 3)] = lsum[i];
            }
            __syncthreads();
            if (tid < 64) {
                const float l = lsw[tid] + lsw[64 + tid] + lsw[128 + tid] + lsw[192 + tid];
                const float lse = 16.0f + __logf(l);
                const int m = m0 + tid;
                const int tt = m >> 5, bb = m & 31;
                const int yvv = y[bb * SS + tt];
                float local = (yvv != 0) ? (lse - tgt64[tid]) / (32.0f * (float)lens[bb]) : 0.f;
                for (int off = 1; off < 64; off <<= 1) local += __shfl_xor(local, off, 64);
                if (tid == 0) atomicAdd(out, local);
            }
        }
    }
}

extern "C" void kernel_launch(void* const* d_in, const int* in_sizes, int n_in,
                              void* d_out, int out_size, void* d_ws, size_t ws_size,
                              hipStream_t stream)
{
    const int*   input_x = (const int*)  d_in[0];
    const int*   input_y = (const int*)  d_in[1];
    const int*   lens    = (const int*)  d_in[2];
    const float* emb_W   = (const float*)d_in[3];
    const float* k0      = (const float*)d_in[4];
    const float* b0      = (const float*)d_in[5];
    const float* k1      = (const float*)d_in[6];
    const float* b1      = (const float*)d_in[7];
    const float* out_W   = (const float*)d_in[8];
    const float* out_b   = (const float*)d_in[9];
    float* out = (float*)d_out;

    char* p = (char*)d_ws;
    ushort_t* Zb   = (ushort_t*)p;  p += (size_t)NROWS * 1024 * 2;    // 33.55 MB
    ushort_t* Xp   = (ushort_t*)p;  p += (size_t)NROWS * 1024 * 2;    // 33.55 MB
    ushort_t* out1 = (ushort_t*)p;  p += (size_t)NROWS * 256 * 2;     // 8.39 MB
    uchar_t*  h2f8 = (uchar_t*)p;   p += (size_t)NROWS * 256;         // 4.19 MB
    uchar_t*  Wsw1 = (uchar_t*)p;   p += (size_t)1024 * 256;          // 256 KB
    uchar_t*  Wsw2 = (uchar_t*)p;   p += (size_t)1024 * 256;          // 256 KB
    ushort_t* W2x  = (ushort_t*)p;  p += (size_t)1024 * 256 * 2;      // 512 KB
    ushort_t* W1xT = (ushort_t*)p;  p += (size_t)1024 * 128 * 2;      // 256 KB
    uchar_t*  Wt8  = (uchar_t*)p;   p += (size_t)NT8 * 4096;          // 2.57 MB
    float*    obp  = (float*)p;     p += (size_t)VPAD * 4;
    unsigned* prog1  = (unsigned*)p; p += 16 * 4;
    unsigned* xflag  = (unsigned*)p; p += 64 * 4;
    unsigned* h2prog = (unsigned*)p; p += 64 * 4;

    hipMemsetAsync(d_out, 0, sizeof(float), stream);
    hipMemsetAsync(prog1, 0, 144 * 4, stream);

    wtx<<<dim3(16, 2), 256, 0, stream>>>(k0, W1xT);
    zgemm_mf<<<dim3(256, 4), 256, 0, stream>>>(W1xT, b0, emb_W, input_x, Zb);
    wf8k128<<<64, 256, 0, stream>>>(k0 + (size_t)EE * 1024, Wsw1);
    wf8k128<<<64, 256, 0, stream>>>(k1 + (size_t)HH * 1024, Wsw2);
    wtgen<<<dim3(16, 4), 256, 0, stream>>>(k1, W2x);
    wtf8<<<NT8, 256, 0, stream>>>(out_W, Wt8);
    obset_kernel<<<(VPAD + 255) / 256, 256, 0, stream>>>(out_b, obp);

    pipe_kernel<<<256, 512, 0, stream>>>(Wsw1, Wsw2, W2x, b1, lens, Zb, out1, Xp,
                                         h2f8, Wt8, obp, input_y, out,
                                         prog1, xflag, h2prog);
}

// Round 21
// 1155.214 us; speedup vs baseline: 1.4496x; 1.0329x over previous
//
#include <hip/hip_runtime.h>
#include <hip/hip_fp8.h>
#include <cmath>

#define SS 512
#define BB 32
#define EE 128
#define HH 256
#define VV 10000
#define NROWS (SS*BB)   // 16384
#define VPAD 10048
#define NT8 (VPAD/16)   // 628 fp8 B-tiles

typedef unsigned short ushort_t;
typedef unsigned char uchar_t;
typedef __attribute__((ext_vector_type(8))) short bf16x8;
typedef __attribute__((ext_vector_type(8))) int i32x8;
typedef __attribute__((ext_vector_type(4))) float f32x4;

#define MFMA(a,b,c)  __builtin_amdgcn_mfma_f32_16x16x32_bf16((a),(b),(c),0,0,0)
#define MFMAS(a,b,c) __builtin_amdgcn_mfma_scale_f32_16x16x128_f8f6f4((a),(b),(c),0,0,0,0x7F7F7F7F,0,0x7F7F7F7F)

__device__ __forceinline__ ushort_t f2bf(float x) {
    unsigned u = __float_as_uint(x);
    u = (u + 0x7FFFu + ((u >> 16) & 1u)) >> 16;   // RNE
    return (ushort_t)u;
}
__device__ __forceinline__ float bf2f(ushort_t h) {
    return __uint_as_float(((unsigned)h) << 16);
}
__device__ __forceinline__ uchar_t f2fp8(float x) {
    __hip_fp8_e4m3 t(x);                           // OCP e4m3
    return (uchar_t)t.__x;
}
__device__ __forceinline__ float sigf(float x) { return 1.0f / (1.0f + __expf(-x)); }
__device__ __forceinline__ float tanhf_(float x) { return 1.0f - 2.0f / (__expf(2.0f * x) + 1.0f); }

__device__ __forceinline__ i32x8 ldfrag(const uchar_t* base, int lane) {
    i32x8 r;
    ((uint4*)&r)[0] = *(const uint4*)(base + lane * 16);
    ((uint4*)&r)[1] = *(const uint4*)(base + 1024 + lane * 16);
    return r;
}

__device__ __forceinline__ void pollc(unsigned* p, unsigned target) {
    int it = 0;
    while (__hip_atomic_load(p, __ATOMIC_RELAXED, __HIP_MEMORY_SCOPE_AGENT) < target) {
        __builtin_amdgcn_s_sleep(4);
        if (++it > 50000000) break;    // anti-hang cap
    }
}
__device__ __forceinline__ void reladd(unsigned* p) {
    __hip_atomic_fetch_add(p, 1u, __ATOMIC_RELEASE, __HIP_MEMORY_SCOPE_AGENT);
}

// ---------------- fused prep: wtx | wf8k128 x2 | wtgen | wtf8 | obset ----------------
// All 6 preparations are mutually independent; one launch, role by blockIdx.
__global__ __launch_bounds__(256)
void prep_kernel(const float* __restrict__ k0, const float* __restrict__ k1,
                 const float* __restrict__ out_W, const float* __restrict__ out_b,
                 ushort_t* __restrict__ W1xT, uchar_t* __restrict__ Wsw1,
                 uchar_t* __restrict__ Wsw2, ushort_t* __restrict__ W2x,
                 uchar_t* __restrict__ Wt8, float* __restrict__ obp)
{
    __shared__ float tile[64][65];
    const int blk = blockIdx.x;
    const int tid = threadIdx.x;

    if (blk < 32) {
        // wtx: k0 x-part fp32[128k][1024n] -> bf16 [1024n][128k]
        const int n0 = (blk & 15) * 64, k0_ = (blk >> 4) * 64;
        for (int i = tid; i < 4096; i += 256) {
            const int kk = i >> 6, nn = i & 63;
            tile[kk][nn] = k0[(size_t)(k0_ + kk) * 1024 + n0 + nn];
        }
        __syncthreads();
        for (int i = tid; i < 4096; i += 256) {
            const int nn = i >> 6, kk = i & 63;
            W1xT[(size_t)(n0 + nn) * 128 + k0_ + kk] = f2bf(tile[kk][nn]);
        }
    } else if (blk < 160) {
        // wf8k128: h-part weights -> fp8 K=128 frag layout (R12-validated)
        const bool l2 = (blk >= 96);
        const int nt = l2 ? (blk - 96) : (blk - 32);
        const float* src = l2 ? (k1 + (size_t)HH * 1024) : (k0 + (size_t)EE * 1024);
        uchar_t* dst = l2 ? Wsw2 : Wsw1;
        const int kk = tid >> 7, h = (tid >> 6) & 1, l = tid & 63;
        const int q = l >> 4, n16 = l & 15;
        const int col = (nt >> 4) * 256 + (nt & 15) * 16 + n16;
        uchar_t v[16];
#pragma unroll
        for (int j = 0; j < 16; j++) {
            const int k = kk * 128 + q * 32 + h * 16 + j;
            v[j] = f2fp8(src[(size_t)k * 1024 + col]);
        }
        *(uint4*)&dst[(((size_t)(nt * 2 + kk) * 2 + h) * 64 + l) * 16] = *(uint4*)v;
    } else if (blk < 224) {
        // wtgen: k1 x-part fp32[256k][1024n] -> bf16 [1024n][256k]
        const int r = blk - 160;
        const int n0 = (r & 15) * 64, k0_ = (r >> 4) * 64;
        for (int i = tid; i < 4096; i += 256) {
            const int kk = i >> 6, nn = i & 63;
            tile[kk][nn] = k1[(size_t)(k0_ + kk) * 1024 + n0 + nn];
        }
        __syncthreads();
        for (int i = tid; i < 4096; i += 256) {
            const int nn = i >> 6, kk = i & 63;
            W2x[(size_t)(n0 + nn) * 256 + k0_ + kk] = f2bf(tile[kk][nn]);
        }
    } else if (blk < 224 + NT8) {
        // wtf8: out_W -> fp8 K=128 frag layout, V padded (R14-validated)
        const int nt = blk - 224;
        const int kk = tid >> 7, h = (tid >> 6) & 1, l = tid & 63;
        const int q = l >> 4, n16 = l & 15;
        const int col = nt * 16 + n16;
        uchar_t v[16];
#pragma unroll
        for (int j = 0; j < 16; j++) {
            const int k = kk * 128 + q * 32 + h * 16 + j;
            v[j] = (col < VV) ? f2fp8(out_W[(size_t)k * VV + col]) : (uchar_t)0;
        }
        *(uint4*)&Wt8[(((size_t)(nt * 2 + kk) * 2 + h) * 64 + l) * 16] = *(uint4*)v;
    } else {
        // obset
        const int v = (blk - 224 - NT8) * 256 + tid;
        if (v < VPAD) obp[v] = (v < VV) ? out_b[v] : -INFINITY;
    }
}

// ---------------- MFMA zgemm, gate-interleaved out (R17-validated) ----------------
__global__ __launch_bounds__(256)
void zgemm_mf(const ushort_t* __restrict__ W1xT, const float* __restrict__ b0v,
              const float* __restrict__ emb, const int* __restrict__ idx,
              ushort_t* __restrict__ Zb)
{
    __shared__ ushort_t ash[64 * 136];
    const int tid = threadIdx.x;
    const int w = tid >> 6, lane = tid & 63;
    const int q = lane >> 4, n16 = lane & 15;
    const int m0 = blockIdx.x * 64;
    const int nbase = blockIdx.y * 256;

    for (int i = tid; i < 64 * 32; i += 256) {
        const int r_ = i >> 5, c4 = i & 31;
        const int m = m0 + r_;
        const int t = m >> 5, b = m & 31;
        const int id = idx[b * SS + t];
        const float4 v = ((const float4*)emb)[(size_t)id * 32 + c4];
        ushort_t o4[4] = { f2bf(v.x), f2bf(v.y), f2bf(v.z), f2bf(v.w) };
        *(uint2*)&ash[r_ * 136 + c4 * 4] = *(uint2*)o4;
    }
    __syncthreads();

    bf16x8 A[4];
#pragma unroll
    for (int kb = 0; kb < 4; kb++)
        A[kb] = *(const bf16x8*)&ash[(w * 16 + n16) * 136 + kb * 32 + q * 8];

#pragma unroll 1
    for (int nt = 0; nt < 16; nt++) {
        const int n = nbase + nt * 16 + n16;
        bf16x8 B[4];
#pragma unroll
        for (int kb = 0; kb < 4; kb++)
            B[kb] = *(const bf16x8*)&W1xT[(size_t)n * 128 + kb * 32 + q * 8];
        f32x4 C = (f32x4){0.f, 0.f, 0.f, 0.f};
#pragma unroll
        for (int kb = 0; kb < 4; kb++)
            C = MFMA(A[kb], B[kb], C);
        const float bv = b0v[n];
        const int g = n >> 8, u = n & 255;
#pragma unroll
        for (int r = 0; r < 4; r++)
            Zb[(size_t)(m0 + w * 16 + q * 4 + r) * 1024 + u * 4 + g] = f2bf(C[r] + bv);
    }
}

// ---------------- LSTM recurrence role (R20 + 32-step fences) ----------------
__device__ __forceinline__ void lstm_role(
    uchar_t* Bl, uchar_t* h8buf,
    const uchar_t* __restrict__ Wsw, const ushort_t* __restrict__ zin,
    const int* __restrict__ lens, ushort_t* __restrict__ outp,
    uchar_t* __restrict__ hf8,
    unsigned* prog1, unsigned* xflag, unsigned* h2prog,
    int b, bool isL1)
{
    uchar_t (*h8)[256] = (uchar_t (*)[256])h8buf;
    const int tid = threadIdx.x;
    const int w = tid >> 6, lane = tid & 63;
    const int q = lane >> 4, n16 = lane & 15;
    const int len = lens[b];
    const int jown = q >> 1;
    const int unit = w * 32 + jown * 16 + n16;

#pragma unroll
    for (int li = 0; li < 3; li++) {
        const int nt = li * 16 + w * 2 + 1;
#pragma unroll
        for (int fh = 0; fh < 4; fh++) {
            const size_t s = (((size_t)nt * 4 + fh) * 64 + lane) * 16;
            const size_t d = (((size_t)(w * 3 + li) * 4 + fh) * 64 + lane) * 16;
            *(uint4*)&Bl[d] = *(const uint4*)&Wsw[s];
        }
    }
    i32x8 Bv[4][2];
#pragma unroll
    for (int g = 0; g < 4; g++) {
        const int nt = g * 16 + w * 2;
#pragma unroll
        for (int kk = 0; kk < 2; kk++)
            Bv[g][kk] = ldfrag(&Wsw[(size_t)nt * 4096 + kk * 2048], lane);
    }
    i32x8 Sv[2];                       // tile (3,1) — loop-invariant, VGPR-resident
    {
        const int nt = 3 * 16 + w * 2 + 1;
#pragma unroll
        for (int kk = 0; kk < 2; kk++)
            Sv[kk] = ldfrag(&Wsw[(size_t)nt * 4096 + kk * 2048], lane);
    }
    if (tid < 256) { h8[0][tid] = 0; h8[1][tid] = 0; }
    float c = 0.f;
    __syncthreads();

    const uchar_t* Lb0 = &Bl[(size_t)(w * 3) * 4096];

    uint2 zreg;                        // z prefetch register
    bool zvalid = false;
    if (isL1) {
        zreg = *(const uint2*)&zin[(size_t)(0 * 32 + b) * 1024 + unit * 4];
        zvalid = true;
    }

    for (int t = 0; t < SS; t++) {
        if (t >= len) {                // uniform early exit: zero rest, release rest
            uint4 zz; zz.x = zz.y = zz.z = zz.w = 0u;
            if (outp) {
                const int nseg = (SS - t) * 32;
                for (int i = tid; i < nseg; i += 512) {
                    const int tt = t + (i >> 5), seg = i & 31;
                    *(uint4*)&outp[((size_t)tt * 32 + b) * 256 + seg * 8] = zz;
                }
            }
            if (hf8) {
                const int nseg8 = (SS - t) * 16;
                for (int i = tid; i < nseg8; i += 512) {
                    const int tt = t + (i >> 4), seg = i & 15;
                    *(uint4*)&hf8[((size_t)tt * 32 + b) * 256 + seg * 16] = zz;
                }
            }
            __syncthreads();           // drain zero-fill stores
            if (tid == 0) {
                if (isL1) for (int cc = t >> 5; cc < 16; cc++) reladd(&prog1[cc]);
                else      for (int cc = t >> 3; cc < 64; cc++) reladd(&h2prog[cc]);
            }
            break;
        }
        if (!isL1 && (t & 31) == 0) {  // consume 4 xgemm chunks per fence
            if (tid == 0) {
#pragma unroll
                for (int cc = 0; cc < 4; cc++) pollc(&xflag[(t >> 3) + cc], 1u);
            }
            __syncthreads();
            __builtin_amdgcn_fence(__ATOMIC_ACQUIRE, "agent");
        }
        const size_t row = (size_t)t * 32 + b;
        ushort_t z4[4];
        if (zvalid) *(uint2*)z4 = zreg;
        else        *(uint2*)z4 = *(const uint2*)&zin[row * 1024 + unit * 4];
        // prefetch z for t+1; lstm2 only within the acquired 32-step window.
        if (t + 1 < SS && (isL1 || ((t + 1) & 31) != 0)) {
            zreg = *(const uint2*)&zin[(row + 32) * 1024 + unit * 4];
            zvalid = true;
        } else zvalid = false;

        const int rd = t & 1, wr = rd ^ 1;
        i32x8 Af0, Af1;
        ((uint4*)&Af0)[0] = *(const uint4*)&h8[rd][q * 32];
        ((uint4*)&Af0)[1] = *(const uint4*)&h8[rd][q * 32 + 16];
        ((uint4*)&Af1)[0] = *(const uint4*)&h8[rd][128 + q * 32];
        ((uint4*)&Af1)[1] = *(const uint4*)&h8[rd][128 + q * 32 + 16];

        float gvv[4];
#pragma unroll
        for (int g = 0; g < 4; g++) {
            f32x4 C0 = (f32x4){0.f,0.f,0.f,0.f}, C1 = (f32x4){0.f,0.f,0.f,0.f};
            C0 = MFMAS(Af0, Bv[g][0], C0);
            C0 = MFMAS(Af1, Bv[g][1], C0);
            if (g < 3) {
                const uchar_t* p = Lb0 + (size_t)g * 4096;
                C1 = MFMAS(Af0, ldfrag(p, lane), C1);
                C1 = MFMAS(Af1, ldfrag(p + 2048, lane), C1);
            } else {
                C1 = MFMAS(Af0, Sv[0], C1);
                C1 = MFMAS(Af1, Sv[1], C1);
            }
            gvv[g] = jown ? C1[0] : C0[0];
        }
        {
            const float zi = bf2f(z4[0]) + gvv[0];
            const float zg = bf2f(z4[1]) + gvv[1];
            const float zf = bf2f(z4[2]) + gvv[2];
            const float zo = bf2f(z4[3]) + gvv[3];
            const float cn = sigf(zf + 1.0f) * c + sigf(zi) * tanhf_(zg);
            const float hn = sigf(zo) * tanhf_(cn);
            c = cn;
            const uchar_t h8v = f2fp8(hn);
            h8[wr][unit] = h8v;
            if (outp) outp[row * 256 + unit] = f2bf(hn);
            if (hf8) hf8[row * 256 + unit] = h8v;
        }
        __syncthreads();               // h8[wr] ready + all stores drained
        if (tid == 0) {
            if (isL1) { if (((t + 1) & 31) == 0) reladd(&prog1[t >> 5]); }
            else      { if (((t + 1) & 7)  == 0) reladd(&h2prog[t >> 3]); }
        }
    }
}

// ---------------- fused pipeline kernel: 256 co-resident blocks (R18-20 validated) ----
// blk 0..31: lstm1 | 32..95: xgemm (8 t each) | 96..127: lstm2 | 128..255: ce.
__global__ __launch_bounds__(512, 1)
void pipe_kernel(const uchar_t* __restrict__ Wsw1, const uchar_t* __restrict__ Wsw2,
                 const ushort_t* __restrict__ W2x, const float* __restrict__ b1v,
                 const int* __restrict__ lens, const ushort_t* __restrict__ Zb,
                 ushort_t* __restrict__ out1, ushort_t* __restrict__ Xp,
                 uchar_t* __restrict__ hf8, const uchar_t* __restrict__ Wt8,
                 const float* __restrict__ obp, const int* __restrict__ y,
                 float* __restrict__ out,
                 unsigned* __restrict__ prog1, unsigned* __restrict__ xflag,
                 unsigned* __restrict__ h2prog)
{
    __shared__ uchar_t smem[98816];
    const int tid = threadIdx.x;
    const int blk = blockIdx.x;
    const int w = tid >> 6, lane = tid & 63;
    const int q = lane >> 4, n16 = lane & 15;

    if (blk < 32) {
        lstm_role(smem, smem + 98304, Wsw1, Zb, lens, out1, nullptr,
                  prog1, xflag, h2prog, blk, true);
    } else if (blk < 96) {
        // ---------------- xgemm role: timesteps [b2*8, b2*8+8) ----------------
        ushort_t* ash = (ushort_t*)smem;           // 128 x 264
        const int b2 = blk - 32;
        if (tid == 0) pollc(&prog1[b2 >> 2], 32u);
        __syncthreads();
        __builtin_amdgcn_fence(__ATOMIC_ACQUIRE, "agent");
#pragma unroll 1
        for (int half = 0; half < 2; half++) {
            const int m0 = b2 * 256 + half * 128;
            if (half) __syncthreads();             // protect ash overwrite
            for (int i = tid; i < 128 * 32; i += 512) {
                const int r_ = i >> 5, s_ = i & 31;
                *(uint4*)&ash[r_ * 264 + s_ * 8] =
                    *(const uint4*)&out1[(size_t)(m0 + r_) * 256 + s_ * 8];
            }
            __syncthreads();
#pragma unroll 1
            for (int i = 0; i < 8; i++) {
                const int n = (w * 8 + i) * 16 + n16;
                bf16x8 Bfr[8];
#pragma unroll
                for (int kb = 0; kb < 8; kb++)
                    Bfr[kb] = *(const bf16x8*)&W2x[(size_t)n * 256 + kb * 32 + q * 8];
                const float bval = b1v[n];
                const int g = n >> 8, u = n & 255;
                f32x4 Cc[8];
#pragma unroll
                for (int mt = 0; mt < 8; mt++) {
                    Cc[mt] = (f32x4){0.f, 0.f, 0.f, 0.f};
                    bf16x8 Af[8];
#pragma unroll
                    for (int kb = 0; kb < 8; kb++)
                        Af[kb] = *(const bf16x8*)&ash[(mt * 16 + n16) * 264 + kb * 32 + q * 8];
#pragma unroll
                    for (int kb = 0; kb < 8; kb++)
                        Cc[mt] = MFMA(Af[kb], Bfr[kb], Cc[mt]);
                }
#pragma unroll
                for (int mt = 0; mt < 8; mt++)
#pragma unroll
                    for (int r = 0; r < 4; r++) {
                        const int rrow = m0 + mt * 16 + q * 4 + r;
                        Xp[(size_t)rrow * 1024 + u * 4 + g] = f2bf(Cc[mt][r] + bval);
                    }
            }
        }
        __syncthreads();               // drain Xp stores
        if (tid == 0)
            __hip_atomic_store(&xflag[b2], 1u, __ATOMIC_RELEASE, __HIP_MEMORY_SCOPE_AGENT);
    } else if (blk < 128) {
        lstm_role(smem, smem + 98304, Wsw2, Xp, lens, nullptr, hf8,
                  prog1, xflag, h2prog, blk - 96, false);
    } else {
        // ---------------- ce role: rows [cb*128, +128) ----------------
        float* lsw = (float*)smem;                 // [4][64]
        float* tgt64 = (float*)(smem + 1024);      // [64]
        const int cb = blk - 128;
        if (tid == 0) pollc(&h2prog[cb >> 1], 32u);
        __syncthreads();
        __builtin_amdgcn_fence(__ATOMIC_ACQUIRE, "agent");
#pragma unroll 1
        for (int half = 0; half < 2; half++) {
            const int m0 = cb * 128 + half * 64;
            __syncthreads();           // protect tgt64/lsw reuse
            if (tid < 64) tgt64[tid] = 0.f;
            i32x8 A8[4][2];
            int yv[16];
            float lsum[16];
            if (tid < 256) {
#pragma unroll
                for (int mt = 0; mt < 4; mt++) {
                    const size_t rbase = (size_t)(m0 + mt * 16 + n16) * 256;
#pragma unroll
                    for (int kk = 0; kk < 2; kk++) {
                        ((uint4*)&A8[mt][kk])[0] = *(const uint4*)&hf8[rbase + kk * 128 + q * 32];
                        ((uint4*)&A8[mt][kk])[1] = *(const uint4*)&hf8[rbase + kk * 128 + q * 32 + 16];
                    }
                }
#pragma unroll
                for (int mt = 0; mt < 4; mt++)
#pragma unroll
                    for (int r = 0; r < 4; r++) {
                        const int m = m0 + mt * 16 + q * 4 + r;
                        yv[mt * 4 + r] = y[(m & 31) * SS + (m >> 5)];
                    }
#pragma unroll
                for (int i = 0; i < 16; i++) lsum[i] = 0.f;
            }
            __syncthreads();           // tgt64 init visible
            if (tid < 256) {
                for (int tile = 0; tile < 157; tile++) {
                    const int nt = w * 157 + tile;
                    const int n = nt * 16 + n16;
                    const i32x8 B0 = ldfrag(&Wt8[(size_t)(nt * 2 + 0) * 2048], lane);
                    const i32x8 B1 = ldfrag(&Wt8[(size_t)(nt * 2 + 1) * 2048], lane);
                    const float obv = obp[n];
                    f32x4 C[4];
#pragma unroll
                    for (int mt = 0; mt < 4; mt++) {
                        C[mt] = (f32x4){0.f, 0.f, 0.f, 0.f};
                        C[mt] = MFMAS(A8[mt][0], B0, C[mt]);
                        C[mt] = MFMAS(A8[mt][1], B1, C[mt]);
                    }
#pragma unroll
                    for (int mt = 0; mt < 4; mt++)
#pragma unroll
                        for (int r = 0; r < 4; r++) {
                            const float sc = C[mt][r] + obv;
                            if (n == yv[mt * 4 + r]) tgt64[mt * 16 + q * 4 + r] = sc;
                            lsum[mt * 4 + r] += __expf(sc - 16.0f);
                        }
                }
#pragma unroll
                for (int i = 0; i < 16; i++) {
                    float v = lsum[i];
                    v += __shfl_xor(v, 1, 16); v += __shfl_xor(v, 2, 16);
                    v += __shfl_xor(v, 4, 16); v += __shfl_xor(v, 8, 16);
                    lsum[i] = v;
                }
                if (n16 == 0)
#pragma unroll
                    for (int i = 0; i < 16; i++)
                        lsw[w * 64 + (i >> 2) * 16 + q * 4 + (i & 3)] = lsum[i];
            }
            __syncthreads();
            if (tid < 64) {
                const float l = lsw[tid] + lsw[64 + tid] + lsw[128 + tid] + lsw[192 + tid];
                const float lse = 16.0f + __logf(l);
                const int m = m0 + tid;
                const int tt = m >> 5, bb = m & 31;
                const int yvv = y[bb * SS + tt];
                float local = (yvv != 0) ? (lse - tgt64[tid]) / (32.0f * (float)lens[bb]) : 0.f;
                for (int off = 1; off < 64; off <<= 1) local += __shfl_xor(local, off, 64);
                if (tid == 0) atomicAdd(out, local);
            }
        }
    }
}

extern "C" void kernel_launch(void* const* d_in, const int* in_sizes, int n_in,
                              void* d_out, int out_size, void* d_ws, size_t ws_size,
                              hipStream_t stream)
{
    const int*   input_x = (const int*)  d_in[0];
    const int*   input_y = (const int*)  d_in[1];
    const int*   lens    = (const int*)  d_in[2];
    const float* emb_W   = (const float*)d_in[3];
    const float* k0      = (const float*)d_in[4];
    const float* b0      = (const float*)d_in[5];
    const float* k1      = (const float*)d_in[6];
    const float* b1      = (const float*)d_in[7];
    const float* out_W   = (const float*)d_in[8];
    const float* out_b   = (const float*)d_in[9];
    float* out = (float*)d_out;

    char* p = (char*)d_ws;
    ushort_t* Zb   = (ushort_t*)p;  p += (size_t)NROWS * 1024 * 2;    // 33.55 MB
    ushort_t* Xp   = (ushort_t*)p;  p += (size_t)NROWS * 1024 * 2;    // 33.55 MB
    ushort_t* out1 = (ushort_t*)p;  p += (size_t)NROWS * 256 * 2;     // 8.39 MB
    uchar_t*  h2f8 = (uchar_t*)p;   p += (size_t)NROWS * 256;         // 4.19 MB
    uchar_t*  Wsw1 = (uchar_t*)p;   p += (size_t)1024 * 256;          // 256 KB
    uchar_t*  Wsw2 = (uchar_t*)p;   p += (size_t)1024 * 256;          // 256 KB
    ushort_t* W2x  = (ushort_t*)p;  p += (size_t)1024 * 256 * 2;      // 512 KB
    ushort_t* W1xT = (ushort_t*)p;  p += (size_t)1024 * 128 * 2;      // 256 KB
    uchar_t*  Wt8  = (uchar_t*)p;   p += (size_t)NT8 * 4096;          // 2.57 MB
    float*    obp  = (float*)p;     p += (size_t)VPAD * 4;
    unsigned* prog1  = (unsigned*)p; p += 16 * 4;
    unsigned* xflag  = (unsigned*)p; p += 64 * 4;
    unsigned* h2prog = (unsigned*)p; p += 64 * 4;

    hipMemsetAsync(d_out, 0, sizeof(float), stream);
    hipMemsetAsync(prog1, 0, 144 * 4, stream);

    prep_kernel<<<224 + NT8 + 40, 256, 0, stream>>>(k0, k1, out_W, out_b,
                                                    W1xT, Wsw1, Wsw2, W2x, Wt8, obp);
    zgemm_mf<<<dim3(256, 4), 256, 0, stream>>>(W1xT, b0, emb_W, input_x, Zb);
    pipe_kernel<<<256, 512, 0, stream>>>(Wsw1, Wsw2, W2x, b1, lens, Zb, out1, Xp,
                                         h2f8, Wt8, obp, input_y, out,
                                         prog1, xflag, h2prog);
}